// Round 1
// baseline (3207.645 us; speedup 1.0000x reference)
//
#include <hip/hip_runtime.h>
#include <hip/hip_bf16.h>
#include <cstdint>
#include <cstddef>

// Problem constants: data (4,8,4096,3) -> 32 batches x 4096 points
#define BT 32
#define N1 4096
#define S1 256
#define S2 128
#define KNB 32

__device__ __forceinline__ float sqdist(float ax, float ay, float az,
                                        float bx, float by, float bz) {
    // exact replication of sum((a-b)**2, axis=-1): mul then left-to-right add, NO fma
    float dx = __fsub_rn(ax, bx), dy = __fsub_rn(ay, by), dz = __fsub_rn(az, bz);
    return __fadd_rn(__fadd_rn(__fmul_rn(dx, dx), __fmul_rn(dy, dy)), __fmul_rn(dz, dz));
}

// ---------------- FPS module 1: N=4096 -> 256 selected, one block per batch ----------
__global__ __launch_bounds__(256) void fps1_kernel(const float* __restrict__ xyz,
                                                   float* __restrict__ nxz) {
    const int b = blockIdx.x, tid = threadIdx.x;
    const float* X = xyz + (size_t)b * (N1 * 3);
    float px[16], py[16], pz[16], md[16];
#pragma unroll
    for (int j = 0; j < 16; ++j) {
        int i = tid + 256 * j;
        px[j] = X[i * 3 + 0]; py[j] = X[i * 3 + 1]; pz[j] = X[i * 3 + 2];
        md[j] = 1e10f;
    }
    __shared__ float s_l[3];
    __shared__ float s_wv[4];
    __shared__ int   s_wi[4];
    if (tid == 0) {
        s_l[0] = X[0]; s_l[1] = X[1]; s_l[2] = X[2];
        nxz[(size_t)b * S1 * 3 + 0] = X[0];
        nxz[(size_t)b * S1 * 3 + 1] = X[1];
        nxz[(size_t)b * S1 * 3 + 2] = X[2];
    }
    __syncthreads();
    for (int t = 1; t < S1; ++t) {
        float lx = s_l[0], ly = s_l[1], lz = s_l[2];
        float bv = -1.0f; int bi = 0;
#pragma unroll
        for (int j = 0; j < 16; ++j) {
            float d = sqdist(px[j], py[j], pz[j], lx, ly, lz);
            float m = fminf(md[j], d);
            md[j] = m;
            if (m > bv) { bv = m; bi = tid + 256 * j; }   // ascending idx, strict > keeps first max
        }
#pragma unroll
        for (int off = 32; off > 0; off >>= 1) {
            float ov = __shfl_down(bv, off);
            int   oi = __shfl_down(bi, off);
            if (ov > bv || (ov == bv && oi < bi)) { bv = ov; bi = oi; }
        }
        if ((tid & 63) == 0) { s_wv[tid >> 6] = bv; s_wi[tid >> 6] = bi; }
        __syncthreads();
        if (tid == 0) {
            float v = s_wv[0]; int vi = s_wi[0];
#pragma unroll
            for (int w = 1; w < 4; ++w)
                if (s_wv[w] > v || (s_wv[w] == v && s_wi[w] < vi)) { v = s_wv[w]; vi = s_wi[w]; }
            float cx = X[vi * 3 + 0], cy = X[vi * 3 + 1], cz = X[vi * 3 + 2];
            s_l[0] = cx; s_l[1] = cy; s_l[2] = cz;
            nxz[((size_t)b * S1 + t) * 3 + 0] = cx;
            nxz[((size_t)b * S1 + t) * 3 + 1] = cy;
            nxz[((size_t)b * S1 + t) * 3 + 2] = cz;
        }
        __syncthreads();
    }
}

// ---------------- FPS module 2: N=256 -> 128 selected ----------
__global__ __launch_bounds__(256) void fps2_kernel(const float* __restrict__ xyz1,
                                                   float* __restrict__ nxz2) {
    const int b = blockIdx.x, tid = threadIdx.x;
    const float* X = xyz1 + (size_t)b * (S1 * 3);
    float px = X[tid * 3 + 0], py = X[tid * 3 + 1], pz = X[tid * 3 + 2];
    float md = 1e10f;
    __shared__ float s_l[3];
    __shared__ float s_wv[4];
    __shared__ int   s_wi[4];
    if (tid == 0) {
        s_l[0] = X[0]; s_l[1] = X[1]; s_l[2] = X[2];
        nxz2[(size_t)b * S2 * 3 + 0] = X[0];
        nxz2[(size_t)b * S2 * 3 + 1] = X[1];
        nxz2[(size_t)b * S2 * 3 + 2] = X[2];
    }
    __syncthreads();
    for (int t = 1; t < S2; ++t) {
        float d = sqdist(px, py, pz, s_l[0], s_l[1], s_l[2]);
        md = fminf(md, d);
        float bv = md; int bi = tid;
#pragma unroll
        for (int off = 32; off > 0; off >>= 1) {
            float ov = __shfl_down(bv, off);
            int   oi = __shfl_down(bi, off);
            if (ov > bv || (ov == bv && oi < bi)) { bv = ov; bi = oi; }
        }
        if ((tid & 63) == 0) { s_wv[tid >> 6] = bv; s_wi[tid >> 6] = bi; }
        __syncthreads();
        if (tid == 0) {
            float v = s_wv[0]; int vi = s_wi[0];
#pragma unroll
            for (int w = 1; w < 4; ++w)
                if (s_wv[w] > v || (s_wv[w] == v && s_wi[w] < vi)) { v = s_wv[w]; vi = s_wi[w]; }
            float cx = X[vi * 3 + 0], cy = X[vi * 3 + 1], cz = X[vi * 3 + 2];
            s_l[0] = cx; s_l[1] = cy; s_l[2] = cz;
            nxz2[((size_t)b * S2 + t) * 3 + 0] = cx;
            nxz2[((size_t)b * S2 + t) * 3 + 1] = cy;
            nxz2[((size_t)b * S2 + t) * 3 + 2] = cz;
        }
        __syncthreads();
    }
}

// ---------------- Ball query 1: 4096 pts, 256 centers/batch, r=0.2 ----------
__global__ __launch_bounds__(256) void ballq1_kernel(const float* __restrict__ xyz,
                                                     const float* __restrict__ nxz,
                                                     int* __restrict__ gidx) {
    __shared__ float sx[N1], sy[N1], sz[N1];
    const int b = blockIdx.x, tid = threadIdx.x;
    const float* X = xyz + (size_t)b * (N1 * 3);
    for (int i = tid; i < N1; i += 256) {
        sx[i] = X[i * 3 + 0]; sy[i] = X[i * 3 + 1]; sz[i] = X[i * 3 + 2];
    }
    __syncthreads();
    const int s = tid;
    const float* C = nxz + ((size_t)b * S1 + s) * 3;
    const float cx = C[0], cy = C[1], cz = C[2];
    const float r2 = (float)(0.2 * 0.2);   // scalar promoted exactly like the reference
    int* G = gidx + ((size_t)b * S1 + s) * KNB;
    int cnt = 0, first = 0;
    for (int j = 0; j < N1; ++j) {
        float d2 = sqdist(cx, cy, cz, sx[j], sy[j], sz[j]);
        if (d2 < r2) {
            if (cnt == 0) first = j;
            G[cnt] = j;
            if (++cnt == KNB) break;
        }
    }
    for (int p = cnt; p < KNB; ++p) G[p] = first;  // pad with first hit (0 if none)
}

// ---------------- Ball query 2: 256 pts, 128 centers/batch, r=0.4 ----------
__global__ __launch_bounds__(128) void ballq2_kernel(const float* __restrict__ xyz1,
                                                     const float* __restrict__ nxz2,
                                                     int* __restrict__ gidx) {
    __shared__ float sx[S1], sy[S1], sz[S1];
    const int b = blockIdx.x, tid = threadIdx.x;
    const float* X = xyz1 + (size_t)b * (S1 * 3);
    for (int i = tid; i < S1; i += 128) {
        sx[i] = X[i * 3 + 0]; sy[i] = X[i * 3 + 1]; sz[i] = X[i * 3 + 2];
    }
    __syncthreads();
    const int s = tid;
    const float* C = nxz2 + ((size_t)b * S2 + s) * 3;
    const float cx = C[0], cy = C[1], cz = C[2];
    const float r2 = (float)(0.4 * 0.4);
    int* G = gidx + ((size_t)b * S2 + s) * KNB;
    int cnt = 0, first = 0;
    for (int j = 0; j < S1; ++j) {
        float d2 = sqdist(cx, cy, cz, sx[j], sy[j], sz[j]);
        if (d2 < r2) {
            if (cnt == 0) first = j;
            G[cnt] = j;
            if (++cnt == KNB) break;
        }
    }
    for (int p = cnt; p < KNB; ++p) G[p] = first;
}

// ---------------- MLP module 1: per (b,s): gather 32 nbrs, 3->64->64->128, maxpool ----
__global__ __launch_bounds__(256) void mlp1_kernel(
    const float* __restrict__ xyz, const float* __restrict__ nxz,
    const int* __restrict__ gidx,
    const float* __restrict__ w0, const float* __restrict__ b0,
    const float* __restrict__ w1, const float* __restrict__ b1,
    const float* __restrict__ w2, const float* __restrict__ b2,
    float* __restrict__ feat1) {
    const int bs = blockIdx.x;      // b*256 + s
    const int b = bs >> 8;
    const int tid = threadIdx.x;
    __shared__ float s_in[32 * 3];
    __shared__ float hA[32 * 65];    // stride 65 (odd) -> conflict-free
    __shared__ float hB[32 * 65];
    __shared__ float hC[32 * 129];
    const int* G = gidx + (size_t)bs * KNB;
    const float* C0 = nxz + (size_t)bs * 3;
    if (tid < 96) {
        int k = tid / 3, c = tid - 3 * k;
        int j = G[k];
        s_in[k * 3 + c] = __fsub_rn(xyz[((size_t)b * N1 + j) * 3 + c], C0[c]);
    }
    __syncthreads();
    // L1: 3 -> 64
    for (int e = tid; e < 32 * 64; e += 256) {
        int o = e & 63, k = e >> 6;
        float acc = b0[o];
        acc = fmaf(s_in[k * 3 + 0], w0[o * 3 + 0], acc);
        acc = fmaf(s_in[k * 3 + 1], w0[o * 3 + 1], acc);
        acc = fmaf(s_in[k * 3 + 2], w0[o * 3 + 2], acc);
        hA[k * 65 + o] = fmaxf(acc, 0.f);
    }
    __syncthreads();
    // L2: 64 -> 64, per-thread: fixed k, 8 outputs
    {
        const int k = tid & 31, o0 = tid >> 5;
        const float* xr = hA + k * 65;
        float acc[8];
#pragma unroll
        for (int i = 0; i < 8; ++i) acc[i] = b1[o0 + 8 * i];
#pragma unroll 4
        for (int c = 0; c < 64; ++c) {
            float xv = xr[c];
#pragma unroll
            for (int i = 0; i < 8; ++i) acc[i] = fmaf(xv, w1[(o0 + 8 * i) * 64 + c], acc[i]);
        }
#pragma unroll
        for (int i = 0; i < 8; ++i) hB[k * 65 + o0 + 8 * i] = fmaxf(acc[i], 0.f);
    }
    __syncthreads();
    // L3: 64 -> 128
    {
        const int k = tid & 31, o0 = tid >> 5;
        const float* xr = hB + k * 65;
        float acc[16];
#pragma unroll
        for (int i = 0; i < 16; ++i) acc[i] = b2[o0 + 8 * i];
#pragma unroll 4
        for (int c = 0; c < 64; ++c) {
            float xv = xr[c];
#pragma unroll
            for (int i = 0; i < 16; ++i) acc[i] = fmaf(xv, w2[(o0 + 8 * i) * 64 + c], acc[i]);
        }
#pragma unroll
        for (int i = 0; i < 16; ++i) hC[k * 129 + o0 + 8 * i] = fmaxf(acc[i], 0.f);
    }
    __syncthreads();
    if (tid < 128) {
        int o = tid;
        float m = 0.f;
#pragma unroll
        for (int kk = 0; kk < 32; ++kk) m = fmaxf(m, hC[kk * 129 + o]);
        feat1[(size_t)bs * 128 + o] = m;
    }
}

// ---------------- MLP module 2: per (b,s): gather 32 nbrs (3+128ch), 131->128->128->256, maxpool
__global__ __launch_bounds__(256) void mlp2_kernel(
    const float* __restrict__ xyz1, const float* __restrict__ nxz2,
    const int* __restrict__ gidx2, const float* __restrict__ feat1,
    const float* __restrict__ w0, const float* __restrict__ b0,
    const float* __restrict__ w1, const float* __restrict__ b1,
    const float* __restrict__ w2, const float* __restrict__ b2,
    float* __restrict__ feat2) {
    const int bs = blockIdx.x;  // b*128 + s
    const int b = bs >> 7;
    const int tid = threadIdx.x;
    __shared__ float smem[12512];
    float* s_in = smem;          // 32 x 131, stride 133
    float* h1 = smem + 4256;     // 32 x 128, stride 129
    float* h2 = smem + 8384;     // 32 x 128, stride 129
    float* h3 = smem;            // 32 x 256, stride 257 — reuses s_in+h1 region (8224 <= 8384)
    const int* G = gidx2 + (size_t)bs * KNB;
    const float* ctr = nxz2 + (size_t)bs * 3;
    for (int e = tid; e < 32 * 131; e += 256) {
        int k = e / 131, c = e - k * 131;
        int j = G[k];
        float v;
        if (c < 3) v = __fsub_rn(xyz1[((size_t)b * S1 + j) * 3 + c], ctr[c]);
        else       v = feat1[((size_t)b * S1 + j) * 128 + (c - 3)];
        s_in[k * 133 + c] = v;
    }
    __syncthreads();
    // L1: 131 -> 128
    {
        const int k = tid & 31, o0 = tid >> 5;
        const float* xr = s_in + k * 133;
        float acc[16];
#pragma unroll
        for (int i = 0; i < 16; ++i) acc[i] = b0[o0 + 8 * i];
#pragma unroll 2
        for (int c = 0; c < 131; ++c) {
            float xv = xr[c];
#pragma unroll
            for (int i = 0; i < 16; ++i) acc[i] = fmaf(xv, w0[(o0 + 8 * i) * 131 + c], acc[i]);
        }
#pragma unroll
        for (int i = 0; i < 16; ++i) h1[k * 129 + o0 + 8 * i] = fmaxf(acc[i], 0.f);
    }
    __syncthreads();
    // L2: 128 -> 128
    {
        const int k = tid & 31, o0 = tid >> 5;
        const float* xr = h1 + k * 129;
        float acc[16];
#pragma unroll
        for (int i = 0; i < 16; ++i) acc[i] = b1[o0 + 8 * i];
#pragma unroll 2
        for (int c = 0; c < 128; ++c) {
            float xv = xr[c];
#pragma unroll
            for (int i = 0; i < 16; ++i) acc[i] = fmaf(xv, w1[(o0 + 8 * i) * 128 + c], acc[i]);
        }
#pragma unroll
        for (int i = 0; i < 16; ++i) h2[k * 129 + o0 + 8 * i] = fmaxf(acc[i], 0.f);
    }
    __syncthreads();
    // L3: 128 -> 256 (writes into reused region; only h2 is read here, no overlap)
    {
        const int k = tid & 31, o0 = tid >> 5;
        const float* xr = h2 + k * 129;
        float acc[32];
#pragma unroll
        for (int i = 0; i < 32; ++i) acc[i] = b2[o0 + 8 * i];
        for (int c = 0; c < 128; ++c) {
            float xv = xr[c];
#pragma unroll
            for (int i = 0; i < 32; ++i) acc[i] = fmaf(xv, w2[(o0 + 8 * i) * 128 + c], acc[i]);
        }
#pragma unroll
        for (int i = 0; i < 32; ++i) h3[k * 257 + o0 + 8 * i] = fmaxf(acc[i], 0.f);
    }
    __syncthreads();
    {
        int o = tid;
        float m = 0.f;
#pragma unroll
        for (int kk = 0; kk < 32; ++kk) m = fmaxf(m, h3[kk * 257 + o]);
        feat2[(size_t)bs * 256 + o] = m;
    }
}

// ---------------- Module 3 layer 0: concat(xyz(3), feat(256)) -> 256, per 32-row x 64-col tile
__global__ __launch_bounds__(256) void l30_kernel(const float* __restrict__ nxz2,
                                                  const float* __restrict__ f2,
                                                  const float* __restrict__ w,
                                                  const float* __restrict__ bias,
                                                  float* __restrict__ out) {
    __shared__ float sx[32 * 259];
    const int bn0 = blockIdx.x * 32;  // over 32*128 = 4096 rows
    const int ob = blockIdx.y * 64;
    const int tid = threadIdx.x;
    for (int r = 0; r < 32; ++r) {
        int bn = bn0 + r;
        if (tid < 3) sx[r * 259 + tid] = nxz2[(size_t)bn * 3 + tid];
        sx[r * 259 + 3 + tid] = f2[(size_t)bn * 256 + tid];
    }
    __syncthreads();
    const int bnl = tid & 31, og = tid >> 5;
    const float* xr = sx + bnl * 259;
    float acc[8];
#pragma unroll
    for (int i = 0; i < 8; ++i) acc[i] = bias[ob + og + 8 * i];
#pragma unroll 2
    for (int c = 0; c < 259; ++c) {
        float xv = xr[c];
#pragma unroll
        for (int i = 0; i < 8; ++i) acc[i] = fmaf(xv, w[(size_t)(ob + og + 8 * i) * 259 + c], acc[i]);
    }
    float* orow = out + (size_t)(bn0 + bnl) * 256 + ob + og;
#pragma unroll
    for (int i = 0; i < 8; ++i) orow[8 * i] = fmaxf(acc[i], 0.f);
}

// ---------------- Module 3 generic layer: ROWS x 64 output tile, full-CIN LDS staging ----
template <int CIN, int ROWS, int COUT>
__global__ __launch_bounds__(256) void l3_layer_kernel(const float* __restrict__ x,
                                                       const float* __restrict__ w,
                                                       const float* __restrict__ bias,
                                                       float* __restrict__ out) {
    constexpr int CP = (CIN & 1) ? CIN : CIN + 1;
    constexpr int OGN = 256 / ROWS;   // # distinct og values
    constexpr int P = 64 / OGN;       // outputs per thread
    __shared__ float sx[ROWS * CP];
    const int bn0 = blockIdx.x * ROWS;
    const int ob = blockIdx.y * 64;
    const int tid = threadIdx.x;
    for (int r = 0; r < ROWS; ++r) {
        const float* src = x + (size_t)(bn0 + r) * CIN;
        for (int c = tid; c < CIN; c += 256) sx[r * CP + c] = src[c];
    }
    __syncthreads();
    const int bnl = tid & (ROWS - 1), og = tid / ROWS;
    const float* xr = sx + bnl * CP;
    float acc[P];
#pragma unroll
    for (int i = 0; i < P; ++i) acc[i] = bias[ob + og + OGN * i];
#pragma unroll 2
    for (int c = 0; c < CIN; ++c) {
        float xv = xr[c];
#pragma unroll
        for (int i = 0; i < P; ++i)
            acc[i] = fmaf(xv, w[(size_t)(ob + og + OGN * i) * CIN + c], acc[i]);
    }
    float* orow = out + (size_t)(bn0 + bnl) * COUT + ob + og;
#pragma unroll
    for (int i = 0; i < P; ++i) orow[OGN * i] = fmaxf(acc[i], 0.f);
}

// ---------------- Final max over the 128 points ----------------
__global__ __launch_bounds__(256) void maxn_kernel(const float* __restrict__ h,
                                                   float* __restrict__ out) {
    int id = blockIdx.x * 256 + threadIdx.x;  // 32*1024
    int o = id & 1023, b = id >> 10;
    const float* p = h + (size_t)b * 128 * 1024 + o;
    float m = 0.f;   // relu'd values are >= 0
    for (int n = 0; n < 128; ++n) m = fmaxf(m, p[(size_t)n * 1024]);
    out[id] = m;
}

extern "C" void kernel_launch(void* const* d_in, const int* in_sizes, int n_in,
                              void* d_out, int out_size, void* d_ws, size_t ws_size,
                              hipStream_t stream) {
    const float* data = (const float*)d_in[0];
    const float* w10 = (const float*)d_in[1];  const float* b10 = (const float*)d_in[2];
    const float* w11 = (const float*)d_in[3];  const float* b11 = (const float*)d_in[4];
    const float* w12 = (const float*)d_in[5];  const float* b12 = (const float*)d_in[6];
    const float* w20 = (const float*)d_in[7];  const float* b20 = (const float*)d_in[8];
    const float* w21 = (const float*)d_in[9];  const float* b21 = (const float*)d_in[10];
    const float* w22 = (const float*)d_in[11]; const float* b22 = (const float*)d_in[12];
    const float* w30 = (const float*)d_in[13]; const float* b30 = (const float*)d_in[14];
    const float* w31 = (const float*)d_in[15]; const float* b31 = (const float*)d_in[16];
    const float* w32 = (const float*)d_in[17]; const float* b32 = (const float*)d_in[18];
    float* out = (float*)d_out;

    char* ws = (char*)d_ws;
    size_t off = 0;
    auto alloc = [&](size_t bytes) -> void* {
        void* p = ws + off;
        off += (bytes + 255) & ~(size_t)255;
        return p;
    };
    float* nxz1 = (float*)alloc((size_t)BT * S1 * 3 * 4);
    int*   g1   = (int*)  alloc((size_t)BT * S1 * KNB * 4);
    float* f1   = (float*)alloc((size_t)BT * S1 * 128 * 4);
    float* nxz2 = (float*)alloc((size_t)BT * S2 * 3 * 4);
    int*   g2   = (int*)  alloc((size_t)BT * S2 * KNB * 4);
    float* f2   = (float*)alloc((size_t)BT * S2 * 256 * 4);
    float* h3a  = (float*)alloc((size_t)BT * S2 * 256 * 4);
    float* h3b  = (float*)alloc((size_t)BT * S2 * 512 * 4);
    float* h3c  = (float*)alloc((size_t)BT * S2 * 1024 * 4);

    fps1_kernel<<<BT, 256, 0, stream>>>(data, nxz1);
    ballq1_kernel<<<BT, 256, 0, stream>>>(data, nxz1, g1);
    mlp1_kernel<<<BT * S1, 256, 0, stream>>>(data, nxz1, g1, w10, b10, w11, b11, w12, b12, f1);
    fps2_kernel<<<BT, 256, 0, stream>>>(nxz1, nxz2);
    ballq2_kernel<<<BT, 128, 0, stream>>>(nxz1, nxz2, g2);
    mlp2_kernel<<<BT * S2, 256, 0, stream>>>(nxz1, nxz2, g2, f1, w20, b20, w21, b21, w22, b22, f2);
    l30_kernel<<<dim3(BT * S2 / 32, 4), 256, 0, stream>>>(nxz2, f2, w30, b30, h3a);
    l3_layer_kernel<256, 32, 512><<<dim3(BT * S2 / 32, 8), 256, 0, stream>>>(h3a, w31, b31, h3b);
    l3_layer_kernel<512, 16, 1024><<<dim3(BT * S2 / 16, 16), 256, 0, stream>>>(h3b, w32, b32, h3c);
    maxn_kernel<<<BT * 1024 / 256, 256, 0, stream>>>(h3c, out);
}

// Round 2
// 1797.392 us; speedup vs baseline: 1.7846x; 1.7846x over previous
//
#include <hip/hip_runtime.h>
#include <hip/hip_bf16.h>
#include <cstdint>
#include <cstddef>

// Problem constants: data (4,8,4096,3) -> 32 batches x 4096 points
#define BT 32
#define N1 4096
#define S1 256
#define S2 128
#define KNB 32

__device__ __forceinline__ float sqdist(float ax, float ay, float az,
                                        float bx, float by, float bz) {
    // exact replication of sum((a-b)**2, axis=-1): mul then left-to-right add, NO fma
    float dx = __fsub_rn(ax, bx), dy = __fsub_rn(ay, by), dz = __fsub_rn(az, bz);
    return __fadd_rn(__fadd_rn(__fmul_rn(dx, dx), __fmul_rn(dy, dy)), __fmul_rn(dz, dz));
}

// ---------------- FPS module 1: N=4096 -> 256 selected, one block per batch ----------
__global__ __launch_bounds__(256) void fps1_kernel(const float* __restrict__ xyz,
                                                   float* __restrict__ nxz) {
    const int b = blockIdx.x, tid = threadIdx.x;
    const float* X = xyz + (size_t)b * (N1 * 3);
    float px[16], py[16], pz[16], md[16];
#pragma unroll
    for (int j = 0; j < 16; ++j) {
        int i = tid + 256 * j;
        px[j] = X[i * 3 + 0]; py[j] = X[i * 3 + 1]; pz[j] = X[i * 3 + 2];
        md[j] = 1e10f;
    }
    __shared__ float s_l[3];
    __shared__ float s_wv[4];
    __shared__ int   s_wi[4];
    if (tid == 0) {
        s_l[0] = X[0]; s_l[1] = X[1]; s_l[2] = X[2];
        nxz[(size_t)b * S1 * 3 + 0] = X[0];
        nxz[(size_t)b * S1 * 3 + 1] = X[1];
        nxz[(size_t)b * S1 * 3 + 2] = X[2];
    }
    __syncthreads();
    for (int t = 1; t < S1; ++t) {
        float lx = s_l[0], ly = s_l[1], lz = s_l[2];
        float bv = -1.0f; int bi = 0;
#pragma unroll
        for (int j = 0; j < 16; ++j) {
            float d = sqdist(px[j], py[j], pz[j], lx, ly, lz);
            float m = fminf(md[j], d);
            md[j] = m;
            if (m > bv) { bv = m; bi = tid + 256 * j; }   // ascending idx, strict > keeps first max
        }
#pragma unroll
        for (int off = 32; off > 0; off >>= 1) {
            float ov = __shfl_down(bv, off);
            int   oi = __shfl_down(bi, off);
            if (ov > bv || (ov == bv && oi < bi)) { bv = ov; bi = oi; }
        }
        if ((tid & 63) == 0) { s_wv[tid >> 6] = bv; s_wi[tid >> 6] = bi; }
        __syncthreads();
        if (tid == 0) {
            float v = s_wv[0]; int vi = s_wi[0];
#pragma unroll
            for (int w = 1; w < 4; ++w)
                if (s_wv[w] > v || (s_wv[w] == v && s_wi[w] < vi)) { v = s_wv[w]; vi = s_wi[w]; }
            float cx = X[vi * 3 + 0], cy = X[vi * 3 + 1], cz = X[vi * 3 + 2];
            s_l[0] = cx; s_l[1] = cy; s_l[2] = cz;
            nxz[((size_t)b * S1 + t) * 3 + 0] = cx;
            nxz[((size_t)b * S1 + t) * 3 + 1] = cy;
            nxz[((size_t)b * S1 + t) * 3 + 2] = cz;
        }
        __syncthreads();
    }
}

// ---------------- FPS module 2: N=256 -> 128 selected ----------
__global__ __launch_bounds__(256) void fps2_kernel(const float* __restrict__ xyz1,
                                                   float* __restrict__ nxz2) {
    const int b = blockIdx.x, tid = threadIdx.x;
    const float* X = xyz1 + (size_t)b * (S1 * 3);
    float px = X[tid * 3 + 0], py = X[tid * 3 + 1], pz = X[tid * 3 + 2];
    float md = 1e10f;
    __shared__ float s_l[3];
    __shared__ float s_wv[4];
    __shared__ int   s_wi[4];
    if (tid == 0) {
        s_l[0] = X[0]; s_l[1] = X[1]; s_l[2] = X[2];
        nxz2[(size_t)b * S2 * 3 + 0] = X[0];
        nxz2[(size_t)b * S2 * 3 + 1] = X[1];
        nxz2[(size_t)b * S2 * 3 + 2] = X[2];
    }
    __syncthreads();
    for (int t = 1; t < S2; ++t) {
        float d = sqdist(px, py, pz, s_l[0], s_l[1], s_l[2]);
        md = fminf(md, d);
        float bv = md; int bi = tid;
#pragma unroll
        for (int off = 32; off > 0; off >>= 1) {
            float ov = __shfl_down(bv, off);
            int   oi = __shfl_down(bi, off);
            if (ov > bv || (ov == bv && oi < bi)) { bv = ov; bi = oi; }
        }
        if ((tid & 63) == 0) { s_wv[tid >> 6] = bv; s_wi[tid >> 6] = bi; }
        __syncthreads();
        if (tid == 0) {
            float v = s_wv[0]; int vi = s_wi[0];
#pragma unroll
            for (int w = 1; w < 4; ++w)
                if (s_wv[w] > v || (s_wv[w] == v && s_wi[w] < vi)) { v = s_wv[w]; vi = s_wi[w]; }
            float cx = X[vi * 3 + 0], cy = X[vi * 3 + 1], cz = X[vi * 3 + 2];
            s_l[0] = cx; s_l[1] = cy; s_l[2] = cz;
            nxz2[((size_t)b * S2 + t) * 3 + 0] = cx;
            nxz2[((size_t)b * S2 + t) * 3 + 1] = cy;
            nxz2[((size_t)b * S2 + t) * 3 + 2] = cz;
        }
        __syncthreads();
    }
}

// ---------------- Ball query 1: 4096 pts, 256 centers/batch, r=0.2 ----------
__global__ __launch_bounds__(256) void ballq1_kernel(const float* __restrict__ xyz,
                                                     const float* __restrict__ nxz,
                                                     int* __restrict__ gidx) {
    __shared__ float sx[N1], sy[N1], sz[N1];
    const int b = blockIdx.x, tid = threadIdx.x;
    const float* X = xyz + (size_t)b * (N1 * 3);
    for (int i = tid; i < N1; i += 256) {
        sx[i] = X[i * 3 + 0]; sy[i] = X[i * 3 + 1]; sz[i] = X[i * 3 + 2];
    }
    __syncthreads();
    const int s = tid;
    const float* C = nxz + ((size_t)b * S1 + s) * 3;
    const float cx = C[0], cy = C[1], cz = C[2];
    const float r2 = (float)(0.2 * 0.2);   // scalar promoted exactly like the reference
    int* G = gidx + ((size_t)b * S1 + s) * KNB;
    int cnt = 0, first = 0;
    for (int j = 0; j < N1; ++j) {
        float d2 = sqdist(cx, cy, cz, sx[j], sy[j], sz[j]);
        if (d2 < r2) {
            if (cnt == 0) first = j;
            G[cnt] = j;
            if (++cnt == KNB) break;
        }
    }
    for (int p = cnt; p < KNB; ++p) G[p] = first;  // pad with first hit (0 if none)
}

// ---------------- Ball query 2: 256 pts, 128 centers/batch, r=0.4 ----------
__global__ __launch_bounds__(128) void ballq2_kernel(const float* __restrict__ xyz1,
                                                     const float* __restrict__ nxz2,
                                                     int* __restrict__ gidx) {
    __shared__ float sx[S1], sy[S1], sz[S1];
    const int b = blockIdx.x, tid = threadIdx.x;
    const float* X = xyz1 + (size_t)b * (S1 * 3);
    for (int i = tid; i < S1; i += 128) {
        sx[i] = X[i * 3 + 0]; sy[i] = X[i * 3 + 1]; sz[i] = X[i * 3 + 2];
    }
    __syncthreads();
    const int s = tid;
    const float* C = nxz2 + ((size_t)b * S2 + s) * 3;
    const float cx = C[0], cy = C[1], cz = C[2];
    const float r2 = (float)(0.4 * 0.4);
    int* G = gidx + ((size_t)b * S2 + s) * KNB;
    int cnt = 0, first = 0;
    for (int j = 0; j < S1; ++j) {
        float d2 = sqdist(cx, cy, cz, sx[j], sy[j], sz[j]);
        if (d2 < r2) {
            if (cnt == 0) first = j;
            G[cnt] = j;
            if (++cnt == KNB) break;
        }
    }
    for (int p = cnt; p < KNB; ++p) G[p] = first;
}

// ---------------- Gather kernels: materialize MLP inputs row-major ----------------
// Xg1[(bs*32+k)][c] = xyz[b][g1[bs][k]][c] - nxz1[bs][c], c<3
__global__ __launch_bounds__(256) void gather1_kernel(const float* __restrict__ xyz,
                                                      const float* __restrict__ nxz,
                                                      const int* __restrict__ g1,
                                                      float* __restrict__ Xg) {
    int u = blockIdx.x * 256 + threadIdx.x;          // < 262144*3
    int r = u / 3, c = u - r * 3;
    int bs = r >> 5;
    int b = bs >> 8;
    int j = g1[r];
    Xg[u] = xyz[((size_t)b * N1 + j) * 3 + c] - nxz[(size_t)bs * 3 + c];
}

// Xg2[(bs*32+k)][c]: c<3 -> xyz1 gathered minus center; else f1 feature
__global__ __launch_bounds__(256) void gather2_kernel(const float* __restrict__ xyz1,
                                                      const float* __restrict__ nxz2,
                                                      const int* __restrict__ g2,
                                                      const float* __restrict__ f1,
                                                      float* __restrict__ Xg) {
    int u = blockIdx.x * 256 + threadIdx.x;          // < 131072*131
    int r = u / 131, c = u - r * 131;
    int bs = r >> 5;
    int b = bs >> 7;
    int j = g2[r];
    float v;
    if (c < 3) v = xyz1[((size_t)b * S1 + j) * 3 + c] - nxz2[(size_t)bs * 3 + c];
    else       v = f1[((size_t)b * S1 + j) * 128 + (c - 3)];
    Xg[u] = v;
}

// Xg3[r][c]: concat(nxz2[r][0:3], f2[r][0:256]) -> 259 cols
__global__ __launch_bounds__(256) void gather3_kernel(const float* __restrict__ nxz2,
                                                      const float* __restrict__ f2,
                                                      float* __restrict__ Xg) {
    int u = blockIdx.x * 256 + threadIdx.x;          // < 4096*259
    int r = u / 259, c = u - r * 259;
    Xg[u] = (c < 3) ? nxz2[(size_t)r * 3 + c] : f2[(size_t)r * 256 + (c - 3)];
}

// ---------------- Tiled fp32 GEMM + bias + ReLU (+ optional 32-row maxpool) ----------
// C[M][N] = relu(X[M][K] * W[N][K]^T + bias[N]); if POOL, output is
// Cp[M/32][N] = max over 32-row groups (groups aligned to BM=64 -> 2 groups/block).
template <int TN, bool POOL>
__global__ __launch_bounds__(256) void gemm_relu_kernel(const float* __restrict__ X,
                                                        const float* __restrict__ W,
                                                        const float* __restrict__ bias,
                                                        float* __restrict__ C,
                                                        int M, int N, int K) {
    constexpr int BN = 16 * TN;          // 64 or 128
    constexpr int BM = 64, BK = 16;
    constexpr int XP = BM + 4;           // 68: keeps float4 alignment, odd-ish banks
    constexpr int WP = BN + 4;
    __shared__ float Xs[BK][XP];
    __shared__ float Ws[BK][WP];
    __shared__ float pools[POOL ? 16 : 1][POOL ? BN : 4];

    const int m0 = blockIdx.x * BM;
    const int n0 = blockIdx.y * BN;
    const int t = threadIdx.x;
    const int tx = t & 15, ty = t >> 4;

    float acc[4][TN];
#pragma unroll
    for (int i = 0; i < 4; ++i)
#pragma unroll
        for (int j = 0; j < TN; ++j) acc[i][j] = 0.f;

    const int nK = (K + BK - 1) / BK;
    for (int kt = 0; kt < nK; ++kt) {
        const int k0 = kt * BK;
        // stage X-tile transposed: Xs[k][m] = X[m0+m][k0+k]; 4 elems/thread
        {
            int m = t >> 2, kq = (t & 3) * 4;
            const float* src = X + (size_t)(m0 + m) * K + k0 + kq;
#pragma unroll
            for (int i = 0; i < 4; ++i) {
                int k = kq + i;
                Xs[k][m] = (k0 + k < K) ? src[i] : 0.f;
            }
        }
        // stage W-tile transposed: Ws[k][n] = W[n0+n][k0+k]; TN elems/thread
        {
            constexpr int TPR = 16 / TN;             // threads per n-row
            int n = t / TPR, kq = (t % TPR) * TN;
            const float* src = W + (size_t)(n0 + n) * K + k0 + kq;
#pragma unroll
            for (int i = 0; i < TN; ++i) {
                int k = kq + i;
                Ws[k][n] = (k0 + k < K) ? src[i] : 0.f;
            }
        }
        __syncthreads();
#pragma unroll
        for (int kk = 0; kk < BK; ++kk) {
            float4 xv = *(const float4*)&Xs[kk][4 * ty];
            float wv[TN];
            *(float4*)&wv[0] = *(const float4*)&Ws[kk][TN * tx];
            if (TN == 8) *(float4*)&wv[4] = *(const float4*)&Ws[kk][TN * tx + 4];
            float xa[4] = {xv.x, xv.y, xv.z, xv.w};
#pragma unroll
            for (int i = 0; i < 4; ++i)
#pragma unroll
                for (int j = 0; j < TN; ++j)
                    acc[i][j] = fmaf(xa[i], wv[j], acc[i][j]);
        }
        __syncthreads();
    }

    float bv[TN];
#pragma unroll
    for (int j = 0; j < TN; ++j) bv[j] = bias[n0 + TN * tx + j];

    if (!POOL) {
#pragma unroll
        for (int i = 0; i < 4; ++i) {
            int row = m0 + 4 * ty + i;
            float o[TN];
#pragma unroll
            for (int j = 0; j < TN; ++j) o[j] = fmaxf(acc[i][j] + bv[j], 0.f);
            float* dst = C + (size_t)row * N + n0 + TN * tx;
            *(float4*)&dst[0] = *(float4*)&o[0];
            if (TN == 8) *(float4*)&dst[4] = *(float4*)&o[4];
        }
    } else {
        float mv[TN];
#pragma unroll
        for (int j = 0; j < TN; ++j) {
            float m = 0.f;
#pragma unroll
            for (int i = 0; i < 4; ++i) m = fmaxf(m, acc[i][j] + bv[j]);
            mv[j] = m;   // relu(x)=max(x,0): init 0 covers it
        }
#pragma unroll
        for (int j = 0; j < TN; ++j) pools[ty][TN * tx + j] = mv[j];
        __syncthreads();
        if (t < 2 * BN) {
            int sl = t / BN, n = t % BN;
            float m = 0.f;
#pragma unroll
            for (int w = 0; w < 8; ++w) m = fmaxf(m, pools[sl * 8 + w][n]);
            C[((size_t)(m0 >> 5) + sl) * N + n0 + n] = m;
        }
    }
}

// ---------------- Final max over the 128 points ----------------
__global__ __launch_bounds__(256) void maxn_kernel(const float* __restrict__ h,
                                                   float* __restrict__ out) {
    int id = blockIdx.x * 256 + threadIdx.x;  // 32*1024
    int o = id & 1023, b = id >> 10;
    const float* p = h + (size_t)b * 128 * 1024 + o;
    float m = 0.f;   // relu'd values are >= 0
    for (int n = 0; n < 128; ++n) m = fmaxf(m, p[(size_t)n * 1024]);
    out[id] = m;
}

extern "C" void kernel_launch(void* const* d_in, const int* in_sizes, int n_in,
                              void* d_out, int out_size, void* d_ws, size_t ws_size,
                              hipStream_t stream) {
    const float* data = (const float*)d_in[0];
    const float* w10 = (const float*)d_in[1];  const float* b10 = (const float*)d_in[2];
    const float* w11 = (const float*)d_in[3];  const float* b11 = (const float*)d_in[4];
    const float* w12 = (const float*)d_in[5];  const float* b12 = (const float*)d_in[6];
    const float* w20 = (const float*)d_in[7];  const float* b20 = (const float*)d_in[8];
    const float* w21 = (const float*)d_in[9];  const float* b21 = (const float*)d_in[10];
    const float* w22 = (const float*)d_in[11]; const float* b22 = (const float*)d_in[12];
    const float* w30 = (const float*)d_in[13]; const float* b30 = (const float*)d_in[14];
    const float* w31 = (const float*)d_in[15]; const float* b31 = (const float*)d_in[16];
    const float* w32 = (const float*)d_in[17]; const float* b32 = (const float*)d_in[18];
    float* out = (float*)d_out;

    char* ws = (char*)d_ws;
    size_t off = 0;
    auto alloc = [&](size_t bytes) -> void* {
        void* p = ws + off;
        off += (bytes + 255) & ~(size_t)255;
        return p;
    };
    // small buffers
    float* nxz1 = (float*)alloc((size_t)BT * S1 * 3 * 4);
    int*   g1   = (int*)  alloc((size_t)BT * S1 * KNB * 4);
    float* nxz2 = (float*)alloc((size_t)BT * S2 * 3 * 4);
    int*   g2   = (int*)  alloc((size_t)BT * S2 * KNB * 4);
    float* f1   = (float*)alloc((size_t)8192 * 128 * 4);        // 4 MB
    float* f2   = (float*)alloc((size_t)4096 * 256 * 4);        // 4 MB
    float* xg3  = (float*)alloc((size_t)4096 * 259 * 4);        // 4.2 MB
    // big, reused buffers
    float* xg   = (float*)alloc((size_t)131072 * 131 * 4);      // 68.7 MB: Xg1 -> Xg2 -> h3c
    float* bufA = (float*)alloc((size_t)262144 * 64 * 4);       // 67 MB: H1a -> H1b -> h3a
    float* bufB = (float*)alloc((size_t)262144 * 64 * 4);       // 67 MB: H2a -> H2b -> h3b
    float* h3c  = xg;                                           // 4096*1024 fits (16.7MB)
    float* h3a  = bufA;                                         // 4096*256
    float* h3b  = bufB;                                         // 4096*512

    // ---- module 1 ----
    fps1_kernel<<<BT, 256, 0, stream>>>(data, nxz1);
    ballq1_kernel<<<BT, 256, 0, stream>>>(data, nxz1, g1);
    gather1_kernel<<<(262144 * 3) / 256, 256, 0, stream>>>(data, nxz1, g1, xg);
    gemm_relu_kernel<4, false><<<dim3(262144 / 64, 1), 256, 0, stream>>>(xg, w10, b10, bufA, 262144, 64, 3);
    gemm_relu_kernel<4, false><<<dim3(262144 / 64, 1), 256, 0, stream>>>(bufA, w11, b11, bufB, 262144, 64, 64);
    gemm_relu_kernel<8, true><<<dim3(262144 / 64, 1), 256, 0, stream>>>(bufB, w12, b12, f1, 262144, 128, 64);
    // ---- module 2 ----
    fps2_kernel<<<BT, 256, 0, stream>>>(nxz1, nxz2);
    ballq2_kernel<<<BT, 128, 0, stream>>>(nxz1, nxz2, g2);
    gather2_kernel<<<(131072 * 131) / 256, 256, 0, stream>>>(nxz1, nxz2, g2, f1, xg);
    gemm_relu_kernel<8, false><<<dim3(131072 / 64, 1), 256, 0, stream>>>(xg, w20, b20, bufA, 131072, 128, 131);
    gemm_relu_kernel<8, false><<<dim3(131072 / 64, 1), 256, 0, stream>>>(bufA, w21, b21, bufB, 131072, 128, 128);
    gemm_relu_kernel<8, true><<<dim3(131072 / 64, 2), 256, 0, stream>>>(bufB, w22, b22, f2, 131072, 256, 128);
    // ---- module 3 ----
    gather3_kernel<<<(4096 * 259) / 256, 256, 0, stream>>>(nxz2, f2, xg3);
    gemm_relu_kernel<8, false><<<dim3(4096 / 64, 2), 256, 0, stream>>>(xg3, w30, b30, h3a, 4096, 256, 259);
    gemm_relu_kernel<8, false><<<dim3(4096 / 64, 4), 256, 0, stream>>>(h3a, w31, b31, h3b, 4096, 512, 256);
    gemm_relu_kernel<8, false><<<dim3(4096 / 64, 8), 256, 0, stream>>>(h3b, w32, b32, h3c, 4096, 1024, 512);
    maxn_kernel<<<BT * 1024 / 256, 256, 0, stream>>>(h3c, out);
}

// Round 3
// 1426.206 us; speedup vs baseline: 2.2491x; 1.2603x over previous
//
#include <hip/hip_runtime.h>
#include <hip/hip_bf16.h>
#include <cstdint>
#include <cstddef>

// Problem constants: data (4,8,4096,3) -> 32 batches x 4096 points
#define BT 32
#define N1 4096
#define S1 256
#define S2 128
#define KNB 32

__device__ __forceinline__ float sqdist(float ax, float ay, float az,
                                        float bx, float by, float bz) {
    // exact replication of sum((a-b)**2, axis=-1): mul then left-to-right add, NO fma
    float dx = __fsub_rn(ax, bx), dy = __fsub_rn(ay, by), dz = __fsub_rn(az, bz);
    return __fadd_rn(__fadd_rn(__fmul_rn(dx, dx), __fmul_rn(dy, dy)), __fmul_rn(dz, dz));
}

// ---------------- FPS module 1: N=4096 -> 256 selected, one block per batch ----------
__global__ __launch_bounds__(256) void fps1_kernel(const float* __restrict__ xyz,
                                                   float* __restrict__ nxz) {
    const int b = blockIdx.x, tid = threadIdx.x;
    const float* X = xyz + (size_t)b * (N1 * 3);
    float px[16], py[16], pz[16], md[16];
#pragma unroll
    for (int j = 0; j < 16; ++j) {
        int i = tid + 256 * j;
        px[j] = X[i * 3 + 0]; py[j] = X[i * 3 + 1]; pz[j] = X[i * 3 + 2];
        md[j] = 1e10f;
    }
    __shared__ float s_l[3];
    __shared__ float s_wv[4];
    __shared__ int   s_wi[4];
    if (tid == 0) {
        s_l[0] = X[0]; s_l[1] = X[1]; s_l[2] = X[2];
        nxz[(size_t)b * S1 * 3 + 0] = X[0];
        nxz[(size_t)b * S1 * 3 + 1] = X[1];
        nxz[(size_t)b * S1 * 3 + 2] = X[2];
    }
    __syncthreads();
    for (int t = 1; t < S1; ++t) {
        float lx = s_l[0], ly = s_l[1], lz = s_l[2];
        float bv = -1.0f; int bi = 0;
#pragma unroll
        for (int j = 0; j < 16; ++j) {
            float d = sqdist(px[j], py[j], pz[j], lx, ly, lz);
            float m = fminf(md[j], d);
            md[j] = m;
            if (m > bv) { bv = m; bi = tid + 256 * j; }   // ascending idx, strict > keeps first max
        }
#pragma unroll
        for (int off = 32; off > 0; off >>= 1) {
            float ov = __shfl_down(bv, off);
            int   oi = __shfl_down(bi, off);
            if (ov > bv || (ov == bv && oi < bi)) { bv = ov; bi = oi; }
        }
        if ((tid & 63) == 0) { s_wv[tid >> 6] = bv; s_wi[tid >> 6] = bi; }
        __syncthreads();
        if (tid == 0) {
            float v = s_wv[0]; int vi = s_wi[0];
#pragma unroll
            for (int w = 1; w < 4; ++w)
                if (s_wv[w] > v || (s_wv[w] == v && s_wi[w] < vi)) { v = s_wv[w]; vi = s_wi[w]; }
            float cx = X[vi * 3 + 0], cy = X[vi * 3 + 1], cz = X[vi * 3 + 2];
            s_l[0] = cx; s_l[1] = cy; s_l[2] = cz;
            nxz[((size_t)b * S1 + t) * 3 + 0] = cx;
            nxz[((size_t)b * S1 + t) * 3 + 1] = cy;
            nxz[((size_t)b * S1 + t) * 3 + 2] = cz;
        }
        __syncthreads();
    }
}

// ---------------- FPS module 2: N=256 -> 128 selected ----------
__global__ __launch_bounds__(256) void fps2_kernel(const float* __restrict__ xyz1,
                                                   float* __restrict__ nxz2) {
    const int b = blockIdx.x, tid = threadIdx.x;
    const float* X = xyz1 + (size_t)b * (S1 * 3);
    float px = X[tid * 3 + 0], py = X[tid * 3 + 1], pz = X[tid * 3 + 2];
    float md = 1e10f;
    __shared__ float s_l[3];
    __shared__ float s_wv[4];
    __shared__ int   s_wi[4];
    if (tid == 0) {
        s_l[0] = X[0]; s_l[1] = X[1]; s_l[2] = X[2];
        nxz2[(size_t)b * S2 * 3 + 0] = X[0];
        nxz2[(size_t)b * S2 * 3 + 1] = X[1];
        nxz2[(size_t)b * S2 * 3 + 2] = X[2];
    }
    __syncthreads();
    for (int t = 1; t < S2; ++t) {
        float d = sqdist(px, py, pz, s_l[0], s_l[1], s_l[2]);
        md = fminf(md, d);
        float bv = md; int bi = tid;
#pragma unroll
        for (int off = 32; off > 0; off >>= 1) {
            float ov = __shfl_down(bv, off);
            int   oi = __shfl_down(bi, off);
            if (ov > bv || (ov == bv && oi < bi)) { bv = ov; bi = oi; }
        }
        if ((tid & 63) == 0) { s_wv[tid >> 6] = bv; s_wi[tid >> 6] = bi; }
        __syncthreads();
        if (tid == 0) {
            float v = s_wv[0]; int vi = s_wi[0];
#pragma unroll
            for (int w = 1; w < 4; ++w)
                if (s_wv[w] > v || (s_wv[w] == v && s_wi[w] < vi)) { v = s_wv[w]; vi = s_wi[w]; }
            float cx = X[vi * 3 + 0], cy = X[vi * 3 + 1], cz = X[vi * 3 + 2];
            s_l[0] = cx; s_l[1] = cy; s_l[2] = cz;
            nxz2[((size_t)b * S2 + t) * 3 + 0] = cx;
            nxz2[((size_t)b * S2 + t) * 3 + 1] = cy;
            nxz2[((size_t)b * S2 + t) * 3 + 2] = cz;
        }
        __syncthreads();
    }
}

// ---------------- Ball query 1 (wave-per-center): 4096 pts, r=0.2, first-32-by-index ----
__global__ __launch_bounds__(256) void ballq1_kernel(const float* __restrict__ xyz,
                                                     const float* __restrict__ nxz,
                                                     int* __restrict__ gidx) {
    const int wid = (blockIdx.x * 256 + threadIdx.x) >> 6;   // global wave id = center id (b*256+s)
    const int lane = threadIdx.x & 63;
    const int b = wid >> 8;
    const float* X = xyz + (size_t)b * (N1 * 3);
    const float* C = nxz + (size_t)wid * 3;
    const float cx = C[0], cy = C[1], cz = C[2];
    const float r2 = (float)(0.2 * 0.2);   // scalar promoted exactly like the reference
    int* G = gidx + (size_t)wid * KNB;
    int cnt = 0, first = 0;
    bool found = false;
    for (int j0 = 0; j0 < N1 && cnt < KNB; j0 += 64) {
        int j = j0 + lane;
        float d2 = sqdist(cx, cy, cz, X[j * 3 + 0], X[j * 3 + 1], X[j * 3 + 2]);
        bool hit = d2 < r2;
        unsigned long long mask = __ballot(hit);
        if (!found && mask) { first = j0 + __builtin_ctzll(mask); found = true; }
        if (hit) {
            int pos = cnt + __popcll(mask & ((1ull << lane) - 1ull));
            if (pos < KNB) G[pos] = j;
        }
        cnt += __popcll(mask);
    }
    if (cnt < KNB) {
        int pad = found ? first : 0;
        if (lane >= cnt && lane < KNB) G[lane] = pad;
    }
}

// ---------------- Ball query 2 (wave-per-center): 256 pts, r=0.4 ----------
__global__ __launch_bounds__(256) void ballq2_kernel(const float* __restrict__ xyz1,
                                                     const float* __restrict__ nxz2,
                                                     int* __restrict__ gidx) {
    const int wid = (blockIdx.x * 256 + threadIdx.x) >> 6;   // center id (b*128+s)
    const int lane = threadIdx.x & 63;
    const int b = wid >> 7;
    const float* X = xyz1 + (size_t)b * (S1 * 3);
    const float* C = nxz2 + (size_t)wid * 3;
    const float cx = C[0], cy = C[1], cz = C[2];
    const float r2 = (float)(0.4 * 0.4);
    int* G = gidx + (size_t)wid * KNB;
    int cnt = 0, first = 0;
    bool found = false;
    for (int j0 = 0; j0 < S1 && cnt < KNB; j0 += 64) {
        int j = j0 + lane;
        float d2 = sqdist(cx, cy, cz, X[j * 3 + 0], X[j * 3 + 1], X[j * 3 + 2]);
        bool hit = d2 < r2;
        unsigned long long mask = __ballot(hit);
        if (!found && mask) { first = j0 + __builtin_ctzll(mask); found = true; }
        if (hit) {
            int pos = cnt + __popcll(mask & ((1ull << lane) - 1ull));
            if (pos < KNB) G[pos] = j;
        }
        cnt += __popcll(mask);
    }
    if (cnt < KNB) {
        int pad = found ? first : 0;
        if (lane >= cnt && lane < KNB) G[lane] = pad;
    }
}

// ---------------- Gather kernels: materialize MLP inputs row-major ----------------
// Xg1[(bs*32+k)][c] = xyz[b][g1[bs][k]][c] - nxz1[bs][c], c<3
__global__ __launch_bounds__(256) void gather1_kernel(const float* __restrict__ xyz,
                                                      const float* __restrict__ nxz,
                                                      const int* __restrict__ g1,
                                                      float* __restrict__ Xg) {
    int u = blockIdx.x * 256 + threadIdx.x;          // < 262144*3
    int r = u / 3, c = u - r * 3;
    int bs = r >> 5;
    int b = bs >> 8;
    int j = g1[r];
    Xg[u] = xyz[((size_t)b * N1 + j) * 3 + c] - nxz[(size_t)bs * 3 + c];
}

// Xg2[(bs*32+k)][c]: c<3 -> xyz1 gathered minus center; else f1 feature
__global__ __launch_bounds__(256) void gather2_kernel(const float* __restrict__ xyz1,
                                                      const float* __restrict__ nxz2,
                                                      const int* __restrict__ g2,
                                                      const float* __restrict__ f1,
                                                      float* __restrict__ Xg) {
    int u = blockIdx.x * 256 + threadIdx.x;          // < 131072*131
    int r = u / 131, c = u - r * 131;
    int bs = r >> 5;
    int b = bs >> 7;
    int j = g2[r];
    float v;
    if (c < 3) v = xyz1[((size_t)b * S1 + j) * 3 + c] - nxz2[(size_t)bs * 3 + c];
    else       v = f1[((size_t)b * S1 + j) * 128 + (c - 3)];
    Xg[u] = v;
}

// Xg3[r][c]: concat(nxz2[r][0:3], f2[r][0:256]) -> 259 cols
__global__ __launch_bounds__(256) void gather3_kernel(const float* __restrict__ nxz2,
                                                      const float* __restrict__ f2,
                                                      float* __restrict__ Xg) {
    int u = blockIdx.x * 256 + threadIdx.x;          // < 4096*259
    int r = u / 259, c = u - r * 259;
    Xg[u] = (c < 3) ? nxz2[(size_t)r * 3 + c] : f2[(size_t)r * 256 + (c - 3)];
}

// ---------------- Tiled fp32 GEMM + bias + ReLU (+ optional 32-row maxpool) ----------
// C[M][N] = relu(X[M][K] * W[N][K]^T + bias[N]); if POOL, output is
// Cp[M/32][N] = max over 32-row groups (groups aligned to BM=64 -> 2 groups/block).
template <int TN, bool POOL>
__global__ __launch_bounds__(256) void gemm_relu_kernel(const float* __restrict__ X,
                                                        const float* __restrict__ W,
                                                        const float* __restrict__ bias,
                                                        float* __restrict__ C,
                                                        int M, int N, int K) {
    constexpr int BN = 16 * TN;          // 64 or 128
    constexpr int BM = 64, BK = 16;
    constexpr int XP = BM + 4;           // 68: keeps float4 alignment, odd-ish banks
    constexpr int WP = BN + 4;
    __shared__ float Xs[BK][XP];
    __shared__ float Ws[BK][WP];
    __shared__ float pools[POOL ? 16 : 1][POOL ? BN : 4];

    const int m0 = blockIdx.x * BM;
    const int n0 = blockIdx.y * BN;
    const int t = threadIdx.x;
    const int tx = t & 15, ty = t >> 4;

    float acc[4][TN];
#pragma unroll
    for (int i = 0; i < 4; ++i)
#pragma unroll
        for (int j = 0; j < TN; ++j) acc[i][j] = 0.f;

    const int nK = (K + BK - 1) / BK;
    for (int kt = 0; kt < nK; ++kt) {
        const int k0 = kt * BK;
        // stage X-tile transposed: Xs[k][m] = X[m0+m][k0+k]; 4 elems/thread
        {
            int m = t >> 2, kq = (t & 3) * 4;
            const float* src = X + (size_t)(m0 + m) * K + k0 + kq;
#pragma unroll
            for (int i = 0; i < 4; ++i) {
                int k = kq + i;
                Xs[k][m] = (k0 + k < K) ? src[i] : 0.f;
            }
        }
        // stage W-tile transposed: Ws[k][n] = W[n0+n][k0+k]; TN elems/thread
        {
            constexpr int TPR = 16 / TN;             // threads per n-row
            int n = t / TPR, kq = (t % TPR) * TN;
            const float* src = W + (size_t)(n0 + n) * K + k0 + kq;
#pragma unroll
            for (int i = 0; i < TN; ++i) {
                int k = kq + i;
                Ws[k][n] = (k0 + k < K) ? src[i] : 0.f;
            }
        }
        __syncthreads();
#pragma unroll
        for (int kk = 0; kk < BK; ++kk) {
            float4 xv = *(const float4*)&Xs[kk][4 * ty];
            float wv[TN];
            *(float4*)&wv[0] = *(const float4*)&Ws[kk][TN * tx];
            if (TN == 8) *(float4*)&wv[4] = *(const float4*)&Ws[kk][TN * tx + 4];
            float xa[4] = {xv.x, xv.y, xv.z, xv.w};
#pragma unroll
            for (int i = 0; i < 4; ++i)
#pragma unroll
                for (int j = 0; j < TN; ++j)
                    acc[i][j] = fmaf(xa[i], wv[j], acc[i][j]);
        }
        __syncthreads();
    }

    float bv[TN];
#pragma unroll
    for (int j = 0; j < TN; ++j) bv[j] = bias[n0 + TN * tx + j];

    if (!POOL) {
#pragma unroll
        for (int i = 0; i < 4; ++i) {
            int row = m0 + 4 * ty + i;
            float o[TN];
#pragma unroll
            for (int j = 0; j < TN; ++j) o[j] = fmaxf(acc[i][j] + bv[j], 0.f);
            float* dst = C + (size_t)row * N + n0 + TN * tx;
            *(float4*)&dst[0] = *(float4*)&o[0];
            if (TN == 8) *(float4*)&dst[4] = *(float4*)&o[4];
        }
    } else {
        float mv[TN];
#pragma unroll
        for (int j = 0; j < TN; ++j) {
            float m = 0.f;
#pragma unroll
            for (int i = 0; i < 4; ++i) m = fmaxf(m, acc[i][j] + bv[j]);
            mv[j] = m;   // relu(x)=max(x,0): init 0 covers it
        }
#pragma unroll
        for (int j = 0; j < TN; ++j) pools[ty][TN * tx + j] = mv[j];
        __syncthreads();
        if (t < 2 * BN) {
            int sl = t / BN, n = t % BN;
            float m = 0.f;
#pragma unroll
            for (int w = 0; w < 8; ++w) m = fmaxf(m, pools[sl * 8 + w][n]);
            C[((size_t)(m0 >> 5) + sl) * N + n0 + n] = m;
        }
    }
}

// ---------------- Final max over the 128 points ----------------
__global__ __launch_bounds__(256) void maxn_kernel(const float* __restrict__ h,
                                                   float* __restrict__ out) {
    int id = blockIdx.x * 256 + threadIdx.x;  // 32*1024
    int o = id & 1023, b = id >> 10;
    const float* p = h + (size_t)b * 128 * 1024 + o;
    float m = 0.f;   // relu'd values are >= 0
    for (int n = 0; n < 128; ++n) m = fmaxf(m, p[(size_t)n * 1024]);
    out[id] = m;
}

extern "C" void kernel_launch(void* const* d_in, const int* in_sizes, int n_in,
                              void* d_out, int out_size, void* d_ws, size_t ws_size,
                              hipStream_t stream) {
    const float* data = (const float*)d_in[0];
    const float* w10 = (const float*)d_in[1];  const float* b10 = (const float*)d_in[2];
    const float* w11 = (const float*)d_in[3];  const float* b11 = (const float*)d_in[4];
    const float* w12 = (const float*)d_in[5];  const float* b12 = (const float*)d_in[6];
    const float* w20 = (const float*)d_in[7];  const float* b20 = (const float*)d_in[8];
    const float* w21 = (const float*)d_in[9];  const float* b21 = (const float*)d_in[10];
    const float* w22 = (const float*)d_in[11]; const float* b22 = (const float*)d_in[12];
    const float* w30 = (const float*)d_in[13]; const float* b30 = (const float*)d_in[14];
    const float* w31 = (const float*)d_in[15]; const float* b31 = (const float*)d_in[16];
    const float* w32 = (const float*)d_in[17]; const float* b32 = (const float*)d_in[18];
    float* out = (float*)d_out;

    char* ws = (char*)d_ws;
    size_t off = 0;
    auto alloc = [&](size_t bytes) -> void* {
        void* p = ws + off;
        off += (bytes + 255) & ~(size_t)255;
        return p;
    };
    // small buffers
    float* nxz1 = (float*)alloc((size_t)BT * S1 * 3 * 4);
    int*   g1   = (int*)  alloc((size_t)BT * S1 * KNB * 4);
    float* nxz2 = (float*)alloc((size_t)BT * S2 * 3 * 4);
    int*   g2   = (int*)  alloc((size_t)BT * S2 * KNB * 4);
    float* f1   = (float*)alloc((size_t)8192 * 128 * 4);        // 4 MB
    float* f2   = (float*)alloc((size_t)4096 * 256 * 4);        // 4 MB
    float* xg3  = (float*)alloc((size_t)4096 * 259 * 4);        // 4.2 MB
    // big, reused buffers
    float* xg   = (float*)alloc((size_t)131072 * 131 * 4);      // 68.7 MB: Xg1 -> Xg2 -> h3c
    float* bufA = (float*)alloc((size_t)262144 * 64 * 4);       // 67 MB: H1a -> H1b -> h3a
    float* bufB = (float*)alloc((size_t)262144 * 64 * 4);       // 67 MB: H2a -> H2b -> h3b
    float* h3c  = xg;                                           // 4096*1024 fits (16.7MB)
    float* h3a  = bufA;                                         // 4096*256
    float* h3b  = bufB;                                         // 4096*512

    // ---- module 1 ----
    fps1_kernel<<<BT, 256, 0, stream>>>(data, nxz1);
    ballq1_kernel<<<(BT * S1) / 4, 256, 0, stream>>>(data, nxz1, g1);
    gather1_kernel<<<(262144 * 3) / 256, 256, 0, stream>>>(data, nxz1, g1, xg);
    gemm_relu_kernel<4, false><<<dim3(262144 / 64, 1), 256, 0, stream>>>(xg, w10, b10, bufA, 262144, 64, 3);
    gemm_relu_kernel<4, false><<<dim3(262144 / 64, 1), 256, 0, stream>>>(bufA, w11, b11, bufB, 262144, 64, 64);
    gemm_relu_kernel<8, true><<<dim3(262144 / 64, 1), 256, 0, stream>>>(bufB, w12, b12, f1, 262144, 128, 64);
    // ---- module 2 ----
    fps2_kernel<<<BT, 256, 0, stream>>>(nxz1, nxz2);
    ballq2_kernel<<<(BT * S2) / 4, 256, 0, stream>>>(nxz1, nxz2, g2);
    gather2_kernel<<<(131072 * 131) / 256, 256, 0, stream>>>(nxz1, nxz2, g2, f1, xg);
    gemm_relu_kernel<8, false><<<dim3(131072 / 64, 1), 256, 0, stream>>>(xg, w20, b20, bufA, 131072, 128, 131);
    gemm_relu_kernel<8, false><<<dim3(131072 / 64, 1), 256, 0, stream>>>(bufA, w21, b21, bufB, 131072, 128, 128);
    gemm_relu_kernel<8, true><<<dim3(131072 / 64, 2), 256, 0, stream>>>(bufB, w22, b22, f2, 131072, 256, 128);
    // ---- module 3 ----
    gather3_kernel<<<(4096 * 259) / 256, 256, 0, stream>>>(nxz2, f2, xg3);
    gemm_relu_kernel<8, false><<<dim3(4096 / 64, 2), 256, 0, stream>>>(xg3, w30, b30, h3a, 4096, 256, 259);
    gemm_relu_kernel<8, false><<<dim3(4096 / 64, 4), 256, 0, stream>>>(h3a, w31, b31, h3b, 4096, 512, 256);
    gemm_relu_kernel<8, false><<<dim3(4096 / 64, 8), 256, 0, stream>>>(h3b, w32, b32, h3c, 4096, 1024, 512);
    maxn_kernel<<<BT * 1024 / 256, 256, 0, stream>>>(h3c, out);
}

// Round 4
// 1229.923 us; speedup vs baseline: 2.6080x; 1.1596x over previous
//
#include <hip/hip_runtime.h>
#include <hip/hip_bf16.h>
#include <cstdint>
#include <cstddef>

// Problem constants: data (4,8,4096,3) -> 32 batches x 4096 points
#define BT 32
#define N1 4096
#define S1 256
#define S2 128
#define KNB 32

__device__ __forceinline__ float sqdist(float ax, float ay, float az,
                                        float bx, float by, float bz) {
    // exact replication of sum((a-b)**2, axis=-1): mul then left-to-right add, NO fma
    float dx = __fsub_rn(ax, bx), dy = __fsub_rn(ay, by), dz = __fsub_rn(az, bz);
    return __fadd_rn(__fadd_rn(__fmul_rn(dx, dx), __fmul_rn(dy, dy)), __fmul_rn(dz, dz));
}

// pack (value, index) for argmax-with-first-index-tie-break: distances are >= 0 so
// float bits are monotonic as uint; on equal value, larger ~idx == smaller idx wins.
__device__ __forceinline__ unsigned long long packvi(float v, int idx) {
    return ((unsigned long long)__float_as_uint(v) << 32) | (unsigned)(~idx);
}

// ---------------- FPS module 1: N=4096 -> 256, one block/batch, 1 barrier/iter ----------
__global__ __launch_bounds__(256) void fps1_kernel(const float* __restrict__ xyz,
                                                   float* __restrict__ nxz) {
    const int b = blockIdx.x, tid = threadIdx.x;
    const int lane = tid & 63, wv = tid >> 6;
    const float* X = xyz + (size_t)b * (N1 * 3);
    __shared__ float sx[N1], sy[N1], sz[N1];
    __shared__ unsigned long long slots[2][4];
    float px[16], py[16], pz[16], md[16];
#pragma unroll
    for (int j = 0; j < 16; ++j) {
        int i = tid + 256 * j;
        float x = X[i * 3 + 0], y = X[i * 3 + 1], z = X[i * 3 + 2];
        sx[i] = x; sy[i] = y; sz[i] = z;
        px[j] = x; py[j] = y; pz[j] = z;
        md[j] = 1e10f;
    }
    if (tid == 0) {
        nxz[(size_t)b * S1 * 3 + 0] = X[0];
        nxz[(size_t)b * S1 * 3 + 1] = X[1];
        nxz[(size_t)b * S1 * 3 + 2] = X[2];
    }
    __syncthreads();
    float lx = sx[0], ly = sy[0], lz = sz[0];
    for (int t = 1; t < S1; ++t) {
        unsigned long long best = 0;
#pragma unroll
        for (int j = 0; j < 16; ++j) {
            float d = sqdist(px[j], py[j], pz[j], lx, ly, lz);
            float m = fminf(md[j], d);
            md[j] = m;
            unsigned long long pk = packvi(m, tid + 256 * j);
            best = pk > best ? pk : best;
        }
#pragma unroll
        for (int off = 32; off > 0; off >>= 1) {
            unsigned long long o = __shfl_xor(best, off);
            best = o > best ? o : best;
        }
        if (lane == 0) slots[t & 1][wv] = best;
        __syncthreads();
        unsigned long long w01 = slots[t & 1][0] > slots[t & 1][1] ? slots[t & 1][0] : slots[t & 1][1];
        unsigned long long w23 = slots[t & 1][2] > slots[t & 1][3] ? slots[t & 1][2] : slots[t & 1][3];
        unsigned long long w = w01 > w23 ? w01 : w23;
        int vi = (int)(~(unsigned)w);
        lx = sx[vi]; ly = sy[vi]; lz = sz[vi];
        if (tid == 0) {
            float* dst = nxz + ((size_t)b * S1 + t) * 3;
            dst[0] = lx; dst[1] = ly; dst[2] = lz;
        }
    }
}

// ---------------- FPS module 2: N=256 -> 128, ONE WAVE per batch, zero barriers ----------
__global__ __launch_bounds__(64) void fps2_kernel(const float* __restrict__ xyz1,
                                                  float* __restrict__ nxz2) {
    const int b = blockIdx.x, lane = threadIdx.x;
    const float* X = xyz1 + (size_t)b * (S1 * 3);
    __shared__ float sx[S1], sy[S1], sz[S1];
    float px[4], py[4], pz[4], md[4];
#pragma unroll
    for (int j = 0; j < 4; ++j) {
        int i = lane + 64 * j;
        float x = X[i * 3 + 0], y = X[i * 3 + 1], z = X[i * 3 + 2];
        sx[i] = x; sy[i] = y; sz[i] = z;
        px[j] = x; py[j] = y; pz[j] = z;
        md[j] = 1e10f;
    }
    if (lane == 0) {
        nxz2[(size_t)b * S2 * 3 + 0] = X[0];
        nxz2[(size_t)b * S2 * 3 + 1] = X[1];
        nxz2[(size_t)b * S2 * 3 + 2] = X[2];
    }
    // single wave: LDS writes above are wave-synchronous; no barrier needed
    float lx = sx[0], ly = sy[0], lz = sz[0];
    for (int t = 1; t < S2; ++t) {
        unsigned long long best = 0;
#pragma unroll
        for (int j = 0; j < 4; ++j) {
            float d = sqdist(px[j], py[j], pz[j], lx, ly, lz);
            float m = fminf(md[j], d);
            md[j] = m;
            unsigned long long pk = packvi(m, lane + 64 * j);
            best = pk > best ? pk : best;
        }
#pragma unroll
        for (int off = 32; off > 0; off >>= 1) {
            unsigned long long o = __shfl_xor(best, off);
            best = o > best ? o : best;
        }
        int vi = (int)(~(unsigned)best);
        lx = sx[vi]; ly = sy[vi]; lz = sz[vi];
        if (lane == 0) {
            float* dst = nxz2 + ((size_t)b * S2 + t) * 3;
            dst[0] = lx; dst[1] = ly; dst[2] = lz;
        }
    }
}

// ---------------- Ball query 1 (wave-per-center): 4096 pts, r=0.2, first-32-by-index ----
__global__ __launch_bounds__(256) void ballq1_kernel(const float* __restrict__ xyz,
                                                     const float* __restrict__ nxz,
                                                     int* __restrict__ gidx) {
    const int wid = (blockIdx.x * 256 + threadIdx.x) >> 6;   // global wave id = center id (b*256+s)
    const int lane = threadIdx.x & 63;
    const int b = wid >> 8;
    const float* X = xyz + (size_t)b * (N1 * 3);
    const float* C = nxz + (size_t)wid * 3;
    const float cx = C[0], cy = C[1], cz = C[2];
    const float r2 = (float)(0.2 * 0.2);   // scalar promoted exactly like the reference
    int* G = gidx + (size_t)wid * KNB;
    int cnt = 0, first = 0;
    bool found = false;
    for (int j0 = 0; j0 < N1 && cnt < KNB; j0 += 64) {
        int j = j0 + lane;
        float d2 = sqdist(cx, cy, cz, X[j * 3 + 0], X[j * 3 + 1], X[j * 3 + 2]);
        bool hit = d2 < r2;
        unsigned long long mask = __ballot(hit);
        if (!found && mask) { first = j0 + __builtin_ctzll(mask); found = true; }
        if (hit) {
            int pos = cnt + __popcll(mask & ((1ull << lane) - 1ull));
            if (pos < KNB) G[pos] = j;
        }
        cnt += __popcll(mask);
    }
    if (cnt < KNB) {
        int pad = found ? first : 0;
        if (lane >= cnt && lane < KNB) G[lane] = pad;
    }
}

// ---------------- Ball query 2 (wave-per-center): 256 pts, r=0.4 ----------
__global__ __launch_bounds__(256) void ballq2_kernel(const float* __restrict__ xyz1,
                                                     const float* __restrict__ nxz2,
                                                     int* __restrict__ gidx) {
    const int wid = (blockIdx.x * 256 + threadIdx.x) >> 6;   // center id (b*128+s)
    const int lane = threadIdx.x & 63;
    const int b = wid >> 7;
    const float* X = xyz1 + (size_t)b * (S1 * 3);
    const float* C = nxz2 + (size_t)wid * 3;
    const float cx = C[0], cy = C[1], cz = C[2];
    const float r2 = (float)(0.4 * 0.4);
    int* G = gidx + (size_t)wid * KNB;
    int cnt = 0, first = 0;
    bool found = false;
    for (int j0 = 0; j0 < S1 && cnt < KNB; j0 += 64) {
        int j = j0 + lane;
        float d2 = sqdist(cx, cy, cz, X[j * 3 + 0], X[j * 3 + 1], X[j * 3 + 2]);
        bool hit = d2 < r2;
        unsigned long long mask = __ballot(hit);
        if (!found && mask) { first = j0 + __builtin_ctzll(mask); found = true; }
        if (hit) {
            int pos = cnt + __popcll(mask & ((1ull << lane) - 1ull));
            if (pos < KNB) G[pos] = j;
        }
        cnt += __popcll(mask);
    }
    if (cnt < KNB) {
        int pad = found ? first : 0;
        if (lane >= cnt && lane < KNB) G[lane] = pad;
    }
}

// ---------------- Gather kernels: materialize MLP inputs row-major ----------------
// Xg1[(bs*32+k)][c] = xyz[b][g1[bs][k]][c] - nxz1[bs][c], c<3
__global__ __launch_bounds__(256) void gather1_kernel(const float* __restrict__ xyz,
                                                      const float* __restrict__ nxz,
                                                      const int* __restrict__ g1,
                                                      float* __restrict__ Xg) {
    int u = blockIdx.x * 256 + threadIdx.x;          // < 262144*3
    int r = u / 3, c = u - r * 3;
    int bs = r >> 5;
    int b = bs >> 8;
    int j = g1[r];
    Xg[u] = xyz[((size_t)b * N1 + j) * 3 + c] - nxz[(size_t)bs * 3 + c];
}

// Xg2[(bs*32+k)][c]: c<3 -> xyz1 gathered minus center; else f1 feature
__global__ __launch_bounds__(256) void gather2_kernel(const float* __restrict__ xyz1,
                                                      const float* __restrict__ nxz2,
                                                      const int* __restrict__ g2,
                                                      const float* __restrict__ f1,
                                                      float* __restrict__ Xg) {
    int u = blockIdx.x * 256 + threadIdx.x;          // < 131072*131
    int r = u / 131, c = u - r * 131;
    int bs = r >> 5;
    int b = bs >> 7;
    int j = g2[r];
    float v;
    if (c < 3) v = xyz1[((size_t)b * S1 + j) * 3 + c] - nxz2[(size_t)bs * 3 + c];
    else       v = f1[((size_t)b * S1 + j) * 128 + (c - 3)];
    Xg[u] = v;
}

// Xg3[r][c]: concat(nxz2[r][0:3], f2[r][0:256]) -> 259 cols
__global__ __launch_bounds__(256) void gather3_kernel(const float* __restrict__ nxz2,
                                                      const float* __restrict__ f2,
                                                      float* __restrict__ Xg) {
    int u = blockIdx.x * 256 + threadIdx.x;          // < 4096*259
    int r = u / 259, c = u - r * 259;
    Xg[u] = (c < 3) ? nxz2[(size_t)r * 3 + c] : f2[(size_t)r * 256 + (c - 3)];
}

// ---------------- Tiled fp32 GEMM + bias + ReLU (+ optional 32-row maxpool) ----------
// C[M][N] = relu(X[M][K] * W[N][K]^T + bias[N]); if POOL, output is
// Cp[M/32][N] = max over 32-row groups (groups aligned to BM=64 -> 2 groups/block).
template <int TN, bool POOL>
__global__ __launch_bounds__(256) void gemm_relu_kernel(const float* __restrict__ X,
                                                        const float* __restrict__ W,
                                                        const float* __restrict__ bias,
                                                        float* __restrict__ C,
                                                        int M, int N, int K) {
    constexpr int BN = 16 * TN;          // 64 or 128
    constexpr int BM = 64, BK = 16;
    constexpr int XP = BM + 4;           // 68: keeps float4 alignment, odd-ish banks
    constexpr int WP = BN + 4;
    __shared__ float Xs[BK][XP];
    __shared__ float Ws[BK][WP];
    __shared__ float pools[POOL ? 16 : 1][POOL ? BN : 4];

    const int m0 = blockIdx.x * BM;
    const int n0 = blockIdx.y * BN;
    const int t = threadIdx.x;
    const int tx = t & 15, ty = t >> 4;

    float acc[4][TN];
#pragma unroll
    for (int i = 0; i < 4; ++i)
#pragma unroll
        for (int j = 0; j < TN; ++j) acc[i][j] = 0.f;

    const int nK = (K + BK - 1) / BK;
    for (int kt = 0; kt < nK; ++kt) {
        const int k0 = kt * BK;
        // stage X-tile transposed: Xs[k][m] = X[m0+m][k0+k]; 4 elems/thread
        {
            int m = t >> 2, kq = (t & 3) * 4;
            const float* src = X + (size_t)(m0 + m) * K + k0 + kq;
#pragma unroll
            for (int i = 0; i < 4; ++i) {
                int k = kq + i;
                Xs[k][m] = (k0 + k < K) ? src[i] : 0.f;
            }
        }
        // stage W-tile transposed: Ws[k][n] = W[n0+n][k0+k]; TN elems/thread
        {
            constexpr int TPR = 16 / TN;             // threads per n-row
            int n = t / TPR, kq = (t % TPR) * TN;
            const float* src = W + (size_t)(n0 + n) * K + k0 + kq;
#pragma unroll
            for (int i = 0; i < TN; ++i) {
                int k = kq + i;
                Ws[k][n] = (k0 + k < K) ? src[i] : 0.f;
            }
        }
        __syncthreads();
#pragma unroll
        for (int kk = 0; kk < BK; ++kk) {
            float4 xv = *(const float4*)&Xs[kk][4 * ty];
            float wv[TN];
            *(float4*)&wv[0] = *(const float4*)&Ws[kk][TN * tx];
            if (TN == 8) *(float4*)&wv[4] = *(const float4*)&Ws[kk][TN * tx + 4];
            float xa[4] = {xv.x, xv.y, xv.z, xv.w};
#pragma unroll
            for (int i = 0; i < 4; ++i)
#pragma unroll
                for (int j = 0; j < TN; ++j)
                    acc[i][j] = fmaf(xa[i], wv[j], acc[i][j]);
        }
        __syncthreads();
    }

    float bv[TN];
#pragma unroll
    for (int j = 0; j < TN; ++j) bv[j] = bias[n0 + TN * tx + j];

    if (!POOL) {
#pragma unroll
        for (int i = 0; i < 4; ++i) {
            int row = m0 + 4 * ty + i;
            float o[TN];
#pragma unroll
            for (int j = 0; j < TN; ++j) o[j] = fmaxf(acc[i][j] + bv[j], 0.f);
            float* dst = C + (size_t)row * N + n0 + TN * tx;
            *(float4*)&dst[0] = *(float4*)&o[0];
            if (TN == 8) *(float4*)&dst[4] = *(float4*)&o[4];
        }
    } else {
        float mv[TN];
#pragma unroll
        for (int j = 0; j < TN; ++j) {
            float m = 0.f;
#pragma unroll
            for (int i = 0; i < 4; ++i) m = fmaxf(m, acc[i][j] + bv[j]);
            mv[j] = m;   // relu(x)=max(x,0): init 0 covers it
        }
#pragma unroll
        for (int j = 0; j < TN; ++j) pools[ty][TN * tx + j] = mv[j];
        __syncthreads();
        if (t < 2 * BN) {
            int sl = t / BN, n = t % BN;
            float m = 0.f;
#pragma unroll
            for (int w = 0; w < 8; ++w) m = fmaxf(m, pools[sl * 8 + w][n]);
            C[((size_t)(m0 >> 5) + sl) * N + n0 + n] = m;
        }
    }
}

// ---------------- Final max over the 128 points ----------------
__global__ __launch_bounds__(256) void maxn_kernel(const float* __restrict__ h,
                                                   float* __restrict__ out) {
    int id = blockIdx.x * 256 + threadIdx.x;  // 32*1024
    int o = id & 1023, b = id >> 10;
    const float* p = h + (size_t)b * 128 * 1024 + o;
    float m = 0.f;   // relu'd values are >= 0
    for (int n = 0; n < 128; ++n) m = fmaxf(m, p[(size_t)n * 1024]);
    out[id] = m;
}

extern "C" void kernel_launch(void* const* d_in, const int* in_sizes, int n_in,
                              void* d_out, int out_size, void* d_ws, size_t ws_size,
                              hipStream_t stream) {
    const float* data = (const float*)d_in[0];
    const float* w10 = (const float*)d_in[1];  const float* b10 = (const float*)d_in[2];
    const float* w11 = (const float*)d_in[3];  const float* b11 = (const float*)d_in[4];
    const float* w12 = (const float*)d_in[5];  const float* b12 = (const float*)d_in[6];
    const float* w20 = (const float*)d_in[7];  const float* b20 = (const float*)d_in[8];
    const float* w21 = (const float*)d_in[9];  const float* b21 = (const float*)d_in[10];
    const float* w22 = (const float*)d_in[11]; const float* b22 = (const float*)d_in[12];
    const float* w30 = (const float*)d_in[13]; const float* b30 = (const float*)d_in[14];
    const float* w31 = (const float*)d_in[15]; const float* b31 = (const float*)d_in[16];
    const float* w32 = (const float*)d_in[17]; const float* b32 = (const float*)d_in[18];
    float* out = (float*)d_out;

    char* ws = (char*)d_ws;
    size_t off = 0;
    auto alloc = [&](size_t bytes) -> void* {
        void* p = ws + off;
        off += (bytes + 255) & ~(size_t)255;
        return p;
    };
    // small buffers
    float* nxz1 = (float*)alloc((size_t)BT * S1 * 3 * 4);
    int*   g1   = (int*)  alloc((size_t)BT * S1 * KNB * 4);
    float* nxz2 = (float*)alloc((size_t)BT * S2 * 3 * 4);
    int*   g2   = (int*)  alloc((size_t)BT * S2 * KNB * 4);
    float* f1   = (float*)alloc((size_t)8192 * 128 * 4);        // 4 MB
    float* f2   = (float*)alloc((size_t)4096 * 256 * 4);        // 4 MB
    float* xg3  = (float*)alloc((size_t)4096 * 259 * 4);        // 4.2 MB
    // big, reused buffers
    float* xg   = (float*)alloc((size_t)131072 * 131 * 4);      // 68.7 MB: Xg1 -> Xg2 -> h3c
    float* bufA = (float*)alloc((size_t)262144 * 64 * 4);       // 67 MB: H1a -> H1b -> h3a
    float* bufB = (float*)alloc((size_t)262144 * 64 * 4);       // 67 MB: H2a -> H2b -> h3b
    float* h3c  = xg;                                           // 4096*1024 fits (16.7MB)
    float* h3a  = bufA;                                         // 4096*256
    float* h3b  = bufB;                                         // 4096*512

    // ---- module 1 ----
    fps1_kernel<<<BT, 256, 0, stream>>>(data, nxz1);
    ballq1_kernel<<<(BT * S1) / 4, 256, 0, stream>>>(data, nxz1, g1);
    gather1_kernel<<<(262144 * 3) / 256, 256, 0, stream>>>(data, nxz1, g1, xg);
    gemm_relu_kernel<4, false><<<dim3(262144 / 64, 1), 256, 0, stream>>>(xg, w10, b10, bufA, 262144, 64, 3);
    gemm_relu_kernel<4, false><<<dim3(262144 / 64, 1), 256, 0, stream>>>(bufA, w11, b11, bufB, 262144, 64, 64);
    gemm_relu_kernel<8, true><<<dim3(262144 / 64, 1), 256, 0, stream>>>(bufB, w12, b12, f1, 262144, 128, 64);
    // ---- module 2 ----
    fps2_kernel<<<BT, 64, 0, stream>>>(nxz1, nxz2);
    ballq2_kernel<<<(BT * S2) / 4, 256, 0, stream>>>(nxz1, nxz2, g2);
    gather2_kernel<<<(131072 * 131) / 256, 256, 0, stream>>>(nxz1, nxz2, g2, f1, xg);
    gemm_relu_kernel<8, false><<<dim3(131072 / 64, 1), 256, 0, stream>>>(xg, w20, b20, bufA, 131072, 128, 131);
    gemm_relu_kernel<8, false><<<dim3(131072 / 64, 1), 256, 0, stream>>>(bufA, w21, b21, bufB, 131072, 128, 128);
    gemm_relu_kernel<8, true><<<dim3(131072 / 64, 2), 256, 0, stream>>>(bufB, w22, b22, f2, 131072, 256, 128);
    // ---- module 3 ----
    gather3_kernel<<<(4096 * 259) / 256, 256, 0, stream>>>(nxz2, f2, xg3);
    gemm_relu_kernel<8, false><<<dim3(4096 / 64, 2), 256, 0, stream>>>(xg3, w30, b30, h3a, 4096, 256, 259);
    gemm_relu_kernel<8, false><<<dim3(4096 / 64, 4), 256, 0, stream>>>(h3a, w31, b31, h3b, 4096, 512, 256);
    gemm_relu_kernel<8, false><<<dim3(4096 / 64, 8), 256, 0, stream>>>(h3b, w32, b32, h3c, 4096, 1024, 512);
    maxn_kernel<<<BT * 1024 / 256, 256, 0, stream>>>(h3c, out);
}

// Round 5
// 649.809 us; speedup vs baseline: 4.9363x; 1.8927x over previous
//
#include <hip/hip_runtime.h>
#include <hip/hip_bf16.h>
#include <cstdint>
#include <cstddef>

// Problem constants: data (4,8,4096,3) -> 32 batches x 4096 points
#define BT 32
#define N1 4096
#define S1 256
#define S2 128
#define KNB 32

typedef __attribute__((ext_vector_type(8))) short short8;   // 8 bf16 in 4 VGPRs
typedef __attribute__((ext_vector_type(4))) float f32x4;

__device__ __forceinline__ float sqdist(float ax, float ay, float az,
                                        float bx, float by, float bz) {
    // exact replication of sum((a-b)**2, axis=-1): mul then left-to-right add, NO fma
    float dx = __fsub_rn(ax, bx), dy = __fsub_rn(ay, by), dz = __fsub_rn(az, bz);
    return __fadd_rn(__fadd_rn(__fmul_rn(dx, dx), __fmul_rn(dy, dy)), __fmul_rn(dz, dz));
}

// bf16 round-to-nearest-even (values here are finite; no NaN handling needed)
__device__ __forceinline__ unsigned short f2bf(float f) {
    unsigned u = __float_as_uint(f);
    return (unsigned short)((u + 0x7FFFu + ((u >> 16) & 1u)) >> 16);
}
__device__ __forceinline__ float bf2f(unsigned short h) {
    return __uint_as_float(((unsigned)h) << 16);
}

// pack (value, index) for argmax-with-first-index-tie-break
__device__ __forceinline__ unsigned long long packvi(float v, int idx) {
    return ((unsigned long long)__float_as_uint(v) << 32) | (unsigned)(~idx);
}

// ---------------- FPS module 1: N=4096 -> 256, one block/batch, 1 barrier/iter ----------
__global__ __launch_bounds__(256) void fps1_kernel(const float* __restrict__ xyz,
                                                   float* __restrict__ nxz) {
    const int b = blockIdx.x, tid = threadIdx.x;
    const int lane = tid & 63, wv = tid >> 6;
    const float* X = xyz + (size_t)b * (N1 * 3);
    __shared__ float sx[N1], sy[N1], sz[N1];
    __shared__ unsigned long long slots[2][4];
    float px[16], py[16], pz[16], md[16];
#pragma unroll
    for (int j = 0; j < 16; ++j) {
        int i = tid + 256 * j;
        float x = X[i * 3 + 0], y = X[i * 3 + 1], z = X[i * 3 + 2];
        sx[i] = x; sy[i] = y; sz[i] = z;
        px[j] = x; py[j] = y; pz[j] = z;
        md[j] = 1e10f;
    }
    if (tid == 0) {
        nxz[(size_t)b * S1 * 3 + 0] = X[0];
        nxz[(size_t)b * S1 * 3 + 1] = X[1];
        nxz[(size_t)b * S1 * 3 + 2] = X[2];
    }
    __syncthreads();
    float lx = sx[0], ly = sy[0], lz = sz[0];
    for (int t = 1; t < S1; ++t) {
        unsigned long long best = 0;
#pragma unroll
        for (int j = 0; j < 16; ++j) {
            float d = sqdist(px[j], py[j], pz[j], lx, ly, lz);
            float m = fminf(md[j], d);
            md[j] = m;
            unsigned long long pk = packvi(m, tid + 256 * j);
            best = pk > best ? pk : best;
        }
#pragma unroll
        for (int off = 32; off > 0; off >>= 1) {
            unsigned long long o = __shfl_xor(best, off);
            best = o > best ? o : best;
        }
        if (lane == 0) slots[t & 1][wv] = best;
        __syncthreads();
        unsigned long long w01 = slots[t & 1][0] > slots[t & 1][1] ? slots[t & 1][0] : slots[t & 1][1];
        unsigned long long w23 = slots[t & 1][2] > slots[t & 1][3] ? slots[t & 1][2] : slots[t & 1][3];
        unsigned long long w = w01 > w23 ? w01 : w23;
        int vi = (int)(~(unsigned)w);
        lx = sx[vi]; ly = sy[vi]; lz = sz[vi];
        if (tid == 0) {
            float* dst = nxz + ((size_t)b * S1 + t) * 3;
            dst[0] = lx; dst[1] = ly; dst[2] = lz;
        }
    }
}

// ---------------- FPS module 2: N=256 -> 128, ONE WAVE per batch, zero barriers ----------
__global__ __launch_bounds__(64) void fps2_kernel(const float* __restrict__ xyz1,
                                                  float* __restrict__ nxz2) {
    const int b = blockIdx.x, lane = threadIdx.x;
    const float* X = xyz1 + (size_t)b * (S1 * 3);
    __shared__ float sx[S1], sy[S1], sz[S1];
    float px[4], py[4], pz[4], md[4];
#pragma unroll
    for (int j = 0; j < 4; ++j) {
        int i = lane + 64 * j;
        float x = X[i * 3 + 0], y = X[i * 3 + 1], z = X[i * 3 + 2];
        sx[i] = x; sy[i] = y; sz[i] = z;
        px[j] = x; py[j] = y; pz[j] = z;
        md[j] = 1e10f;
    }
    if (lane == 0) {
        nxz2[(size_t)b * S2 * 3 + 0] = X[0];
        nxz2[(size_t)b * S2 * 3 + 1] = X[1];
        nxz2[(size_t)b * S2 * 3 + 2] = X[2];
    }
    float lx = sx[0], ly = sy[0], lz = sz[0];
    for (int t = 1; t < S2; ++t) {
        unsigned long long best = 0;
#pragma unroll
        for (int j = 0; j < 4; ++j) {
            float d = sqdist(px[j], py[j], pz[j], lx, ly, lz);
            float m = fminf(md[j], d);
            md[j] = m;
            unsigned long long pk = packvi(m, lane + 64 * j);
            best = pk > best ? pk : best;
        }
#pragma unroll
        for (int off = 32; off > 0; off >>= 1) {
            unsigned long long o = __shfl_xor(best, off);
            best = o > best ? o : best;
        }
        int vi = (int)(~(unsigned)best);
        lx = sx[vi]; ly = sy[vi]; lz = sz[vi];
        if (lane == 0) {
            float* dst = nxz2 + ((size_t)b * S2 + t) * 3;
            dst[0] = lx; dst[1] = ly; dst[2] = lz;
        }
    }
}

// ---------------- Ball query 1 (wave-per-center): 4096 pts, r=0.2, first-32-by-index ----
__global__ __launch_bounds__(256) void ballq1_kernel(const float* __restrict__ xyz,
                                                     const float* __restrict__ nxz,
                                                     int* __restrict__ gidx) {
    const int wid = (blockIdx.x * 256 + threadIdx.x) >> 6;
    const int lane = threadIdx.x & 63;
    const int b = wid >> 8;
    const float* X = xyz + (size_t)b * (N1 * 3);
    const float* C = nxz + (size_t)wid * 3;
    const float cx = C[0], cy = C[1], cz = C[2];
    const float r2 = (float)(0.2 * 0.2);
    int* G = gidx + (size_t)wid * KNB;
    int cnt = 0, first = 0;
    bool found = false;
    for (int j0 = 0; j0 < N1 && cnt < KNB; j0 += 64) {
        int j = j0 + lane;
        float d2 = sqdist(cx, cy, cz, X[j * 3 + 0], X[j * 3 + 1], X[j * 3 + 2]);
        bool hit = d2 < r2;
        unsigned long long mask = __ballot(hit);
        if (!found && mask) { first = j0 + __builtin_ctzll(mask); found = true; }
        if (hit) {
            int pos = cnt + __popcll(mask & ((1ull << lane) - 1ull));
            if (pos < KNB) G[pos] = j;
        }
        cnt += __popcll(mask);
    }
    if (cnt < KNB) {
        int pad = found ? first : 0;
        if (lane >= cnt && lane < KNB) G[lane] = pad;
    }
}

// ---------------- Ball query 2 (wave-per-center): 256 pts, r=0.4 ----------
__global__ __launch_bounds__(256) void ballq2_kernel(const float* __restrict__ xyz1,
                                                     const float* __restrict__ nxz2,
                                                     int* __restrict__ gidx) {
    const int wid = (blockIdx.x * 256 + threadIdx.x) >> 6;
    const int lane = threadIdx.x & 63;
    const int b = wid >> 7;
    const float* X = xyz1 + (size_t)b * (S1 * 3);
    const float* C = nxz2 + (size_t)wid * 3;
    const float cx = C[0], cy = C[1], cz = C[2];
    const float r2 = (float)(0.4 * 0.4);
    int* G = gidx + (size_t)wid * KNB;
    int cnt = 0, first = 0;
    bool found = false;
    for (int j0 = 0; j0 < S1 && cnt < KNB; j0 += 64) {
        int j = j0 + lane;
        float d2 = sqdist(cx, cy, cz, X[j * 3 + 0], X[j * 3 + 1], X[j * 3 + 2]);
        bool hit = d2 < r2;
        unsigned long long mask = __ballot(hit);
        if (!found && mask) { first = j0 + __builtin_ctzll(mask); found = true; }
        if (hit) {
            int pos = cnt + __popcll(mask & ((1ull << lane) - 1ull));
            if (pos < KNB) G[pos] = j;
        }
        cnt += __popcll(mask);
    }
    if (cnt < KNB) {
        int pad = found ? first : 0;
        if (lane >= cnt && lane < KNB) G[lane] = pad;
    }
}

// ---------------- Weight conversion: fp32 -> bf16 arena, K padded to x64 ----------------
// arena layout (element offsets):
//  w11b@0      64x64   (4096)
//  w12b@4096   128x64  (8192)
//  w20b@12288  128x192 (24576, K 131->192)
//  w21b@36864  128x128 (16384)
//  w22b@53248  256x128 (32768)
//  w30b@86016  256x320 (81920, K 259->320)
//  w31b@167936 512x256 (131072)
//  w32b@299008 1024x512(524288)  total 823296
__global__ __launch_bounds__(256) void wconv_kernel(
    const float* __restrict__ w11, const float* __restrict__ w12,
    const float* __restrict__ w20, const float* __restrict__ w21,
    const float* __restrict__ w22, const float* __restrict__ w30,
    const float* __restrict__ w31, const float* __restrict__ w32,
    unsigned short* __restrict__ wb) {
    int u = blockIdx.x * 256 + threadIdx.x;
    if (u >= 823296) return;
    const float* src; int base, Kp, Ko;
    if      (u < 4096)   { src = w11; base = 0;      Kp = 64;  Ko = 64;  }
    else if (u < 12288)  { src = w12; base = 4096;   Kp = 64;  Ko = 64;  }
    else if (u < 36864)  { src = w20; base = 12288;  Kp = 192; Ko = 131; }
    else if (u < 53248)  { src = w21; base = 36864;  Kp = 128; Ko = 128; }
    else if (u < 86016)  { src = w22; base = 53248;  Kp = 128; Ko = 128; }
    else if (u < 167936) { src = w30; base = 86016;  Kp = 320; Ko = 259; }
    else if (u < 299008) { src = w31; base = 167936; Kp = 256; Ko = 256; }
    else                 { src = w32; base = 299008; Kp = 512; Ko = 512; }
    int local = u - base;
    int n = local / Kp, k = local - n * Kp;
    float v = (k < Ko) ? src[(size_t)n * Ko + k] : 0.f;
    wb[u] = f2bf(v);
}

// ---------------- Fused gather1 + layer 1_0 (K=3): one thread per (row, out) -----------
__global__ __launch_bounds__(256) void l11_kernel(const float* __restrict__ xyz,
                                                  const float* __restrict__ nxz,
                                                  const int* __restrict__ g1,
                                                  const float* __restrict__ w0,
                                                  const float* __restrict__ b0,
                                                  unsigned short* __restrict__ out) {
    int id = blockIdx.x * 256 + threadIdx.x;        // < 262144*64
    int row = id >> 6, o = id & 63;
    int bs = row >> 5, b = bs >> 8;
    int j = g1[row];
    const float* P = xyz + ((size_t)b * N1 + j) * 3;
    const float* Cc = nxz + (size_t)bs * 3;
    float x = P[0] - Cc[0], y = P[1] - Cc[1], z = P[2] - Cc[2];
    float acc = b0[o];
    acc = fmaf(x, w0[o * 3 + 0], acc);
    acc = fmaf(y, w0[o * 3 + 1], acc);
    acc = fmaf(z, w0[o * 3 + 2], acc);
    out[id] = f2bf(fmaxf(acc, 0.f));
}

// ---------------- Gather 2: bf16, K padded 131->192 ----------------
__global__ __launch_bounds__(256) void gather2_kernel(const float* __restrict__ xyz1,
                                                      const float* __restrict__ nxz2,
                                                      const int* __restrict__ g2,
                                                      const unsigned short* __restrict__ f1,
                                                      unsigned short* __restrict__ Xg) {
    int u = blockIdx.x * 256 + threadIdx.x;          // < 131072*192
    int r = u / 192, c = u - r * 192;
    int bs = r >> 5, b = bs >> 7;
    int j = g2[r];
    unsigned short v;
    if (c < 3)        v = f2bf(xyz1[((size_t)b * S1 + j) * 3 + c] - nxz2[(size_t)bs * 3 + c]);
    else if (c < 131) v = f1[((size_t)b * S1 + j) * 128 + (c - 3)];
    else              v = 0;
    Xg[u] = v;
}

// ---------------- Gather 3: bf16, K padded 259->320 ----------------
__global__ __launch_bounds__(256) void gather3_kernel(const float* __restrict__ nxz2,
                                                      const unsigned short* __restrict__ f2,
                                                      unsigned short* __restrict__ Xg) {
    int u = blockIdx.x * 256 + threadIdx.x;          // < 4096*320
    int r = u / 320, c = u - r * 320;
    unsigned short v;
    if (c < 3)        v = f2bf(nxz2[(size_t)r * 3 + c]);
    else if (c < 259) v = f2[(size_t)r * 256 + (c - 3)];
    else              v = 0;
    Xg[u] = v;
}

// ---------------- bf16 MFMA GEMM: C = relu(X[MxK] * W[NxK]^T + bias) -------------------
// BM=128, BK=64, 4 waves; wave w owns rows [w*32, w*32+32).
// POOL: output pooled max over 32-row groups -> C[M/32][N].
template <int BN, bool POOL>
__global__ __launch_bounds__(256) void mfma_gemm(const unsigned short* __restrict__ X,
                                                 const unsigned short* __restrict__ W,
                                                 const float* __restrict__ bias,
                                                 unsigned short* __restrict__ C,
                                                 int M, int N, int K) {
    constexpr int BM = 128, BK = 64;
    constexpr int AP = BK + 8;            // row stride 72 bf16 = 144B -> 2-way-only conflicts
    constexpr int NT = BN / 16;
    __shared__ __align__(16) unsigned short As[BM * AP];
    __shared__ __align__(16) unsigned short Bs[BN * AP];
    const int t = threadIdx.x;
    const int lane = t & 63, w = t >> 6;
    const int m0 = blockIdx.x * BM;
    const int n0 = blockIdx.y * BN;
    const int r16 = lane & 15, q = lane >> 4;

    f32x4 acc[2][NT];
#pragma unroll
    for (int i = 0; i < 2; ++i)
#pragma unroll
        for (int j = 0; j < NT; ++j) acc[i][j] = (f32x4){0.f, 0.f, 0.f, 0.f};

    for (int k0 = 0; k0 < K; k0 += BK) {
        // stage A-tile: 128 rows x 64 cols, 16B chunks
        for (int c = t; c < BM * (BK / 8); c += 256) {
            int row = c >> 3, ch = c & 7;
            *(short8*)&As[row * AP + ch * 8] =
                *(const short8*)&X[(size_t)(m0 + row) * K + k0 + ch * 8];
        }
        for (int c = t; c < BN * (BK / 8); c += 256) {
            int row = c >> 3, ch = c & 7;
            *(short8*)&Bs[row * AP + ch * 8] =
                *(const short8*)&W[(size_t)(n0 + row) * K + k0 + ch * 8];
        }
        __syncthreads();
#pragma unroll
        for (int kk = 0; kk < BK; kk += 32) {
            // A frag: lane holds A[m = r16][k = kk + q*8 + j], j=0..7
            short8 a0 = *(const short8*)&As[(w * 32 + r16) * AP + kk + q * 8];
            short8 a1 = *(const short8*)&As[(w * 32 + 16 + r16) * AP + kk + q * 8];
#pragma unroll
            for (int j = 0; j < NT; ++j) {
                short8 bf = *(const short8*)&Bs[(j * 16 + r16) * AP + kk + q * 8];
                acc[0][j] = __builtin_amdgcn_mfma_f32_16x16x32_bf16(a0, bf, acc[0][j], 0, 0, 0);
                acc[1][j] = __builtin_amdgcn_mfma_f32_16x16x32_bf16(a1, bf, acc[1][j], 0, 0, 0);
            }
        }
        __syncthreads();
    }

    // C/D layout: reg r of a 16x16 tile -> row = q*4 + r, col = r16
    if (!POOL) {
#pragma unroll
        for (int i = 0; i < 2; ++i)
#pragma unroll
            for (int j = 0; j < NT; ++j) {
                int col = n0 + j * 16 + r16;
                float bv = bias[col];
#pragma unroll
                for (int r = 0; r < 4; ++r) {
                    int row = m0 + w * 32 + i * 16 + q * 4 + r;
                    float v = fmaxf(acc[i][j][r] + bv, 0.f);
                    C[(size_t)row * N + col] = f2bf(v);
                }
            }
    } else {
        // wave w covers exactly one 32-row pool group: group = m0/32 + w
#pragma unroll
        for (int j = 0; j < NT; ++j) {
            int col = n0 + j * 16 + r16;
            float bv = bias[col];
            float mv = 0.f;
#pragma unroll
            for (int i = 0; i < 2; ++i)
#pragma unroll
                for (int r = 0; r < 4; ++r)
                    mv = fmaxf(mv, acc[i][j][r] + bv);
            mv = fmaxf(mv, __shfl_xor(mv, 16));
            mv = fmaxf(mv, __shfl_xor(mv, 32));
            if (q == 0)
                C[(size_t)((m0 >> 5) + w) * N + col] = f2bf(mv);
        }
    }
}

// ---------------- Final max over the 128 points (bf16 in, fp32 out) ----------------
__global__ __launch_bounds__(256) void maxn_kernel(const unsigned short* __restrict__ h,
                                                   float* __restrict__ out) {
    int id = blockIdx.x * 256 + threadIdx.x;  // 32*1024
    int o = id & 1023, b = id >> 10;
    const unsigned short* p = h + (size_t)b * 128 * 1024 + o;
    float m = 0.f;
    for (int n = 0; n < 128; ++n) m = fmaxf(m, bf2f(p[(size_t)n * 1024]));
    out[id] = m;
}

extern "C" void kernel_launch(void* const* d_in, const int* in_sizes, int n_in,
                              void* d_out, int out_size, void* d_ws, size_t ws_size,
                              hipStream_t stream) {
    const float* data = (const float*)d_in[0];
    const float* w10 = (const float*)d_in[1];  const float* b10 = (const float*)d_in[2];
    const float* w11 = (const float*)d_in[3];  const float* b11 = (const float*)d_in[4];
    const float* w12 = (const float*)d_in[5];  const float* b12 = (const float*)d_in[6];
    const float* w20 = (const float*)d_in[7];  const float* b20 = (const float*)d_in[8];
    const float* w21 = (const float*)d_in[9];  const float* b21 = (const float*)d_in[10];
    const float* w22 = (const float*)d_in[11]; const float* b22 = (const float*)d_in[12];
    const float* w30 = (const float*)d_in[13]; const float* b30 = (const float*)d_in[14];
    const float* w31 = (const float*)d_in[15]; const float* b31 = (const float*)d_in[16];
    const float* w32 = (const float*)d_in[17]; const float* b32 = (const float*)d_in[18];
    float* out = (float*)d_out;

    char* ws = (char*)d_ws;
    size_t off = 0;
    auto alloc = [&](size_t bytes) -> void* {
        void* p = ws + off;
        off += (bytes + 255) & ~(size_t)255;
        return p;
    };
    float* nxz1 = (float*)alloc((size_t)BT * S1 * 3 * 4);
    int*   g1   = (int*)  alloc((size_t)BT * S1 * KNB * 4);
    float* nxz2 = (float*)alloc((size_t)BT * S2 * 3 * 4);
    int*   g2   = (int*)  alloc((size_t)BT * S2 * KNB * 4);
    unsigned short* wb  = (unsigned short*)alloc((size_t)823296 * 2);
    unsigned short* f1  = (unsigned short*)alloc((size_t)8192 * 128 * 2);
    unsigned short* f2  = (unsigned short*)alloc((size_t)4096 * 256 * 2);
    unsigned short* xg3 = (unsigned short*)alloc((size_t)4096 * 320 * 2);
    // big region (67 MB): A1+A2 in module 1; then Xg2 (50.3MB); then C1/C2/C3
    unsigned short* bigA = (unsigned short*)alloc((size_t)2 * 262144 * 64 * 2);
    unsigned short* B1   = (unsigned short*)alloc((size_t)131072 * 128 * 2);
    unsigned short* B2   = (unsigned short*)alloc((size_t)131072 * 128 * 2);

    unsigned short* A1  = bigA;
    unsigned short* A2  = bigA + (size_t)262144 * 64;
    unsigned short* Xg2 = bigA;                         // after A1/A2 dead
    unsigned short* C1  = bigA;                         // 4096*256, after Xg2 dead
    unsigned short* C2  = bigA + (size_t)2 * 1024 * 1024;   // 4096*512
    unsigned short* C3  = bigA + (size_t)6 * 1024 * 1024;   // 4096*1024

    const unsigned short* w11b = wb + 0;
    const unsigned short* w12b = wb + 4096;
    const unsigned short* w20b = wb + 12288;
    const unsigned short* w21b = wb + 36864;
    const unsigned short* w22b = wb + 53248;
    const unsigned short* w30b = wb + 86016;
    const unsigned short* w31b = wb + 167936;
    const unsigned short* w32b = wb + 299008;

    wconv_kernel<<<(823296 + 255) / 256, 256, 0, stream>>>(w11, w12, w20, w21, w22, w30, w31, w32, wb);

    // ---- module 1 ----
    fps1_kernel<<<BT, 256, 0, stream>>>(data, nxz1);
    ballq1_kernel<<<(BT * S1) / 4, 256, 0, stream>>>(data, nxz1, g1);
    l11_kernel<<<(262144 * 64) / 256, 256, 0, stream>>>(data, nxz1, g1, w10, b10, A1);
    mfma_gemm<64, false><<<dim3(262144 / 128, 1), 256, 0, stream>>>(A1, w11b, b11, A2, 262144, 64, 64);
    mfma_gemm<128, true><<<dim3(262144 / 128, 1), 256, 0, stream>>>(A2, w12b, b12, f1, 262144, 128, 64);
    // ---- module 2 ----
    fps2_kernel<<<BT, 64, 0, stream>>>(nxz1, nxz2);
    ballq2_kernel<<<(BT * S2) / 4, 256, 0, stream>>>(nxz1, nxz2, g2);
    gather2_kernel<<<(131072 * 192) / 256, 256, 0, stream>>>(nxz1, nxz2, g2, f1, Xg2);
    mfma_gemm<128, false><<<dim3(131072 / 128, 1), 256, 0, stream>>>(Xg2, w20b, b20, B1, 131072, 128, 192);
    mfma_gemm<128, false><<<dim3(131072 / 128, 1), 256, 0, stream>>>(B1, w21b, b21, B2, 131072, 128, 128);
    mfma_gemm<128, true><<<dim3(131072 / 128, 2), 256, 0, stream>>>(B2, w22b, b22, f2, 131072, 256, 128);
    // ---- module 3 ----
    gather3_kernel<<<(4096 * 320) / 256, 256, 0, stream>>>(nxz2, f2, xg3);
    mfma_gemm<128, false><<<dim3(4096 / 128, 2), 256, 0, stream>>>(xg3, w30b, b30, C1, 4096, 256, 320);
    mfma_gemm<128, false><<<dim3(4096 / 128, 4), 256, 0, stream>>>(C1, w31b, b31, C2, 4096, 512, 256);
    mfma_gemm<128, false><<<dim3(4096 / 128, 8), 256, 0, stream>>>(C2, w32b, b32, C3, 4096, 1024, 512);
    maxn_kernel<<<(BT * 1024) / 256, 256, 0, stream>>>(C3, out);
}

// Round 6
// 556.408 us; speedup vs baseline: 5.7649x; 1.1679x over previous
//
#include <hip/hip_runtime.h>
#include <hip/hip_bf16.h>
#include <cstdint>
#include <cstddef>

// Problem constants: data (4,8,4096,3) -> 32 batches x 4096 points
#define BT 32
#define N1 4096
#define S1 256
#define S2 128
#define KNB 32

typedef __attribute__((ext_vector_type(8))) short short8;   // 8 bf16 in 4 VGPRs
typedef __attribute__((ext_vector_type(4))) float f32x4;

__device__ __forceinline__ float sqdist(float ax, float ay, float az,
                                        float bx, float by, float bz) {
    // exact replication of sum((a-b)**2, axis=-1): mul then left-to-right add, NO fma
    float dx = __fsub_rn(ax, bx), dy = __fsub_rn(ay, by), dz = __fsub_rn(az, bz);
    return __fadd_rn(__fadd_rn(__fmul_rn(dx, dx), __fmul_rn(dy, dy)), __fmul_rn(dz, dz));
}

// bf16 round-to-nearest-even (values here are finite)
__device__ __forceinline__ unsigned short f2bf(float f) {
    unsigned u = __float_as_uint(f);
    return (unsigned short)((u + 0x7FFFu + ((u >> 16) & 1u)) >> 16);
}
__device__ __forceinline__ float bf2f(unsigned short h) {
    return __uint_as_float(((unsigned)h) << 16);
}

// pack (value, index) for argmax-with-first-index-tie-break
__device__ __forceinline__ unsigned long long packvi(float v, int idx) {
    return ((unsigned long long)__float_as_uint(v) << 32) | (unsigned)(~idx);
}

// ---------------- FPS module 1: N=4096 -> 256, one block/batch ----------
// History buffered in LDS; nxz written once at the end (keeps global-store
// drain out of the per-iteration barrier path).
__global__ __launch_bounds__(256) void fps1_kernel(const float* __restrict__ xyz,
                                                   float* __restrict__ nxz) {
    const int b = blockIdx.x, tid = threadIdx.x;
    const int lane = tid & 63, wv = tid >> 6;
    const float* X = xyz + (size_t)b * (N1 * 3);
    __shared__ float sx[N1], sy[N1], sz[N1];
    __shared__ unsigned long long slots[2][4];
    __shared__ float hist[S1 * 3];
    float px[16], py[16], pz[16], md[16];
#pragma unroll
    for (int j = 0; j < 16; ++j) {
        int i = tid + 256 * j;
        float x = X[i * 3 + 0], y = X[i * 3 + 1], z = X[i * 3 + 2];
        sx[i] = x; sy[i] = y; sz[i] = z;
        px[j] = x; py[j] = y; pz[j] = z;
        md[j] = 1e10f;
    }
    if (tid == 0) { hist[0] = X[0]; hist[1] = X[1]; hist[2] = X[2]; }
    __syncthreads();
    float lx = sx[0], ly = sy[0], lz = sz[0];
    for (int t = 1; t < S1; ++t) {
        float bv = -1.0f; int bi = 0;
#pragma unroll
        for (int j = 0; j < 16; ++j) {
            float d = sqdist(px[j], py[j], pz[j], lx, ly, lz);
            float m = fminf(md[j], d);
            md[j] = m;
            if (m > bv) { bv = m; bi = tid + 256 * j; }   // ascending idx: first max kept
        }
        unsigned long long best = packvi(bv, bi);
#pragma unroll
        for (int off = 32; off > 0; off >>= 1) {
            unsigned long long o = __shfl_xor(best, off);
            best = o > best ? o : best;
        }
        if (lane == 0) slots[t & 1][wv] = best;
        __syncthreads();
        unsigned long long w01 = slots[t & 1][0] > slots[t & 1][1] ? slots[t & 1][0] : slots[t & 1][1];
        unsigned long long w23 = slots[t & 1][2] > slots[t & 1][3] ? slots[t & 1][2] : slots[t & 1][3];
        unsigned long long w = w01 > w23 ? w01 : w23;
        int vi = (int)(~(unsigned)w);
        lx = sx[vi]; ly = sy[vi]; lz = sz[vi];
        if (tid == 0) {
            hist[t * 3 + 0] = lx; hist[t * 3 + 1] = ly; hist[t * 3 + 2] = lz;
        }
    }
    __syncthreads();
    for (int u = tid; u < S1 * 3; u += 256) nxz[(size_t)b * S1 * 3 + u] = hist[u];
}

// ---------------- FPS module 2: N=256 -> 128, ONE WAVE per batch ----------
__global__ __launch_bounds__(64) void fps2_kernel(const float* __restrict__ xyz1,
                                                  float* __restrict__ nxz2) {
    const int b = blockIdx.x, lane = threadIdx.x;
    const float* X = xyz1 + (size_t)b * (S1 * 3);
    __shared__ float sx[S1], sy[S1], sz[S1];
    float px[4], py[4], pz[4], md[4];
#pragma unroll
    for (int j = 0; j < 4; ++j) {
        int i = lane + 64 * j;
        float x = X[i * 3 + 0], y = X[i * 3 + 1], z = X[i * 3 + 2];
        sx[i] = x; sy[i] = y; sz[i] = z;
        px[j] = x; py[j] = y; pz[j] = z;
        md[j] = 1e10f;
    }
    if (lane == 0) {
        nxz2[(size_t)b * S2 * 3 + 0] = X[0];
        nxz2[(size_t)b * S2 * 3 + 1] = X[1];
        nxz2[(size_t)b * S2 * 3 + 2] = X[2];
    }
    float lx = sx[0], ly = sy[0], lz = sz[0];
    for (int t = 1; t < S2; ++t) {
        unsigned long long best = 0;
#pragma unroll
        for (int j = 0; j < 4; ++j) {
            float d = sqdist(px[j], py[j], pz[j], lx, ly, lz);
            float m = fminf(md[j], d);
            md[j] = m;
            unsigned long long pk = packvi(m, lane + 64 * j);
            best = pk > best ? pk : best;
        }
#pragma unroll
        for (int off = 32; off > 0; off >>= 1) {
            unsigned long long o = __shfl_xor(best, off);
            best = o > best ? o : best;
        }
        int vi = (int)(~(unsigned)best);
        lx = sx[vi]; ly = sy[vi]; lz = sz[vi];
        if (lane == 0) {
            float* dst = nxz2 + ((size_t)b * S2 + t) * 3;
            dst[0] = lx; dst[1] = ly; dst[2] = lz;
        }
    }
}

// ---------------- Ball query 1 (wave-per-center): 4096 pts, r=0.2 ----------
__global__ __launch_bounds__(256) void ballq1_kernel(const float* __restrict__ xyz,
                                                     const float* __restrict__ nxz,
                                                     int* __restrict__ gidx) {
    const int wid = (blockIdx.x * 256 + threadIdx.x) >> 6;
    const int lane = threadIdx.x & 63;
    const int b = wid >> 8;
    const float* X = xyz + (size_t)b * (N1 * 3);
    const float* C = nxz + (size_t)wid * 3;
    const float cx = C[0], cy = C[1], cz = C[2];
    const float r2 = (float)(0.2 * 0.2);
    int* G = gidx + (size_t)wid * KNB;
    int cnt = 0, first = 0;
    bool found = false;
    for (int j0 = 0; j0 < N1 && cnt < KNB; j0 += 64) {
        int j = j0 + lane;
        float d2 = sqdist(cx, cy, cz, X[j * 3 + 0], X[j * 3 + 1], X[j * 3 + 2]);
        bool hit = d2 < r2;
        unsigned long long mask = __ballot(hit);
        if (!found && mask) { first = j0 + __builtin_ctzll(mask); found = true; }
        if (hit) {
            int pos = cnt + __popcll(mask & ((1ull << lane) - 1ull));
            if (pos < KNB) G[pos] = j;
        }
        cnt += __popcll(mask);
    }
    if (cnt < KNB) {
        int pad = found ? first : 0;
        if (lane >= cnt && lane < KNB) G[lane] = pad;
    }
}

// ---------------- Ball query 2 (wave-per-center): 256 pts, r=0.4 ----------
__global__ __launch_bounds__(256) void ballq2_kernel(const float* __restrict__ xyz1,
                                                     const float* __restrict__ nxz2,
                                                     int* __restrict__ gidx) {
    const int wid = (blockIdx.x * 256 + threadIdx.x) >> 6;
    const int lane = threadIdx.x & 63;
    const int b = wid >> 7;
    const float* X = xyz1 + (size_t)b * (S1 * 3);
    const float* C = nxz2 + (size_t)wid * 3;
    const float cx = C[0], cy = C[1], cz = C[2];
    const float r2 = (float)(0.4 * 0.4);
    int* G = gidx + (size_t)wid * KNB;
    int cnt = 0, first = 0;
    bool found = false;
    for (int j0 = 0; j0 < S1 && cnt < KNB; j0 += 64) {
        int j = j0 + lane;
        float d2 = sqdist(cx, cy, cz, X[j * 3 + 0], X[j * 3 + 1], X[j * 3 + 2]);
        bool hit = d2 < r2;
        unsigned long long mask = __ballot(hit);
        if (!found && mask) { first = j0 + __builtin_ctzll(mask); found = true; }
        if (hit) {
            int pos = cnt + __popcll(mask & ((1ull << lane) - 1ull));
            if (pos < KNB) G[pos] = j;
        }
        cnt += __popcll(mask);
    }
    if (cnt < KNB) {
        int pad = found ? first : 0;
        if (lane >= cnt && lane < KNB) G[lane] = pad;
    }
}

// ---------------- Weight conversion: fp32 -> bf16 arena, K padded to x64 ----------------
// arena layout (element offsets):
//  w11b@0      64x64   | w12b@4096  128x64 | w20p@12288 128x192 (PERMUTED: feat-first)
//  w21b@36864  128x128 | w22b@53248 256x128| w30b@86016 256x320 (259->320)
//  w31b@167936 512x256 | w32b@299008 1024x512  total 823296
__global__ __launch_bounds__(256) void wconv_kernel(
    const float* __restrict__ w11, const float* __restrict__ w12,
    const float* __restrict__ w20, const float* __restrict__ w21,
    const float* __restrict__ w22, const float* __restrict__ w30,
    const float* __restrict__ w31, const float* __restrict__ w32,
    unsigned short* __restrict__ wb) {
    int u = blockIdx.x * 256 + threadIdx.x;
    if (u >= 823296) return;
    const float* src; int base, Kp, Ko; bool perm20 = false;
    if      (u < 4096)   { src = w11; base = 0;      Kp = 64;  Ko = 64;  }
    else if (u < 12288)  { src = w12; base = 4096;   Kp = 64;  Ko = 64;  }
    else if (u < 36864)  { src = w20; base = 12288;  Kp = 192; Ko = 131; perm20 = true; }
    else if (u < 53248)  { src = w21; base = 36864;  Kp = 128; Ko = 128; }
    else if (u < 86016)  { src = w22; base = 53248;  Kp = 128; Ko = 128; }
    else if (u < 167936) { src = w30; base = 86016;  Kp = 320; Ko = 259; }
    else if (u < 299008) { src = w31; base = 167936; Kp = 256; Ko = 256; }
    else                 { src = w32; base = 299008; Kp = 512; Ko = 512; }
    int local = u - base;
    int n = local / Kp, k = local - n * Kp;
    float v;
    if (perm20) {
        // module-2 layer0 columns: [0..127]=w20[.,k+3] (features), [128..130]=w20[.,k-128] (xyz), rest 0
        int ksrc = (k < 128) ? (k + 3) : ((k < 131) ? (k - 128) : -1);
        v = (ksrc >= 0) ? src[(size_t)n * 131 + ksrc] : 0.f;
    } else {
        v = (k < Ko) ? src[(size_t)n * Ko + k] : 0.f;
    }
    wb[u] = f2bf(v);
}

// ---------------- Module 1 fused: gather + L0(K=3, VALU) + L1 + L2 MFMA + pool ---------
// grid 2048 x 256thr; block = 128 rows = 4 centers (pool groups).
__global__ __launch_bounds__(256) void m1_kernel(
    const float* __restrict__ xyz, const float* __restrict__ nxz,
    const int* __restrict__ g1,
    const float* __restrict__ w10, const float* __restrict__ b10,
    const unsigned short* __restrict__ w11b, const float* __restrict__ b11,
    const unsigned short* __restrict__ w12b, const float* __restrict__ b12,
    unsigned short* __restrict__ f1) {
    constexpr int AP = 72;
    __shared__ __align__(16) unsigned short As[128 * AP];
    __shared__ __align__(16) unsigned short Hs[128 * AP];
    __shared__ __align__(16) unsigned short Bs[128 * AP];
    __shared__ float sxyz[128 * 3];
    const int t = threadIdx.x;
    const int lane = t & 63, w = t >> 6;
    const int r16 = lane & 15, q = lane >> 4;
    const int m0 = blockIdx.x * 128;

    // phase 0: row coords + stage w11 (64 rows x 64)
    if (t < 128) {
        int row = m0 + t, bs = row >> 5, b = bs >> 8, j = g1[row];
        const float* P = xyz + ((size_t)b * N1 + j) * 3;
        const float* Cc = nxz + (size_t)bs * 3;
        sxyz[t * 3 + 0] = P[0] - Cc[0];
        sxyz[t * 3 + 1] = P[1] - Cc[1];
        sxyz[t * 3 + 2] = P[2] - Cc[2];
    }
    for (int c = t; c < 64 * 8; c += 256) {
        int row = c >> 3, ch = c & 7;
        *(short8*)&Bs[row * AP + ch * 8] = *(const short8*)&w11b[row * 64 + ch * 8];
    }
    __syncthreads();
    // phase 1: L0 (3 -> 64), 2 threads/row, 32 outputs each
    {
        const int r = t >> 1, half = (t & 1) * 32;
        const float x = sxyz[r * 3 + 0], y = sxyz[r * 3 + 1], z = sxyz[r * 3 + 2];
        unsigned short tmp[32];
#pragma unroll
        for (int o = 0; o < 32; ++o) {
            int oo = half + o;
            float acc = b10[oo];
            acc = fmaf(x, w10[oo * 3 + 0], acc);
            acc = fmaf(y, w10[oo * 3 + 1], acc);
            acc = fmaf(z, w10[oo * 3 + 2], acc);
            tmp[o] = f2bf(fmaxf(acc, 0.f));
        }
#pragma unroll
        for (int c2 = 0; c2 < 4; ++c2)
            *(short8*)&As[r * AP + half + c2 * 8] = *(short8*)&tmp[c2 * 8];
    }
    __syncthreads();
    // phase 2: L1 MFMA (K=64, N=64) -> Hs (relu bf16)
    {
        f32x4 acc[2][4];
#pragma unroll
        for (int i = 0; i < 2; ++i)
#pragma unroll
            for (int j = 0; j < 4; ++j) acc[i][j] = (f32x4){0.f, 0.f, 0.f, 0.f};
#pragma unroll
        for (int kk = 0; kk < 64; kk += 32) {
            short8 a0 = *(const short8*)&As[(w * 32 + r16) * AP + kk + q * 8];
            short8 a1 = *(const short8*)&As[(w * 32 + 16 + r16) * AP + kk + q * 8];
#pragma unroll
            for (int j = 0; j < 4; ++j) {
                short8 bf = *(const short8*)&Bs[(j * 16 + r16) * AP + kk + q * 8];
                acc[0][j] = __builtin_amdgcn_mfma_f32_16x16x32_bf16(a0, bf, acc[0][j], 0, 0, 0);
                acc[1][j] = __builtin_amdgcn_mfma_f32_16x16x32_bf16(a1, bf, acc[1][j], 0, 0, 0);
            }
        }
#pragma unroll
        for (int i = 0; i < 2; ++i)
#pragma unroll
            for (int j = 0; j < 4; ++j) {
                int col = j * 16 + r16;
                float bv = b11[col];
#pragma unroll
                for (int r = 0; r < 4; ++r) {
                    int row = w * 32 + i * 16 + q * 4 + r;
                    Hs[row * AP + col] = f2bf(fmaxf(acc[i][j][r] + bv, 0.f));
                }
            }
    }
    __syncthreads();           // all waves done reading Bs, Hs fully written
    // restage Bs with w12 (128 rows x 64)
    for (int c = t; c < 128 * 8; c += 256) {
        int row = c >> 3, ch = c & 7;
        *(short8*)&Bs[row * AP + ch * 8] = *(const short8*)&w12b[row * 64 + ch * 8];
    }
    __syncthreads();
    // phase 3: L2 MFMA (K=64, N=128) + pool -> f1
    {
        f32x4 acc[2][8];
#pragma unroll
        for (int i = 0; i < 2; ++i)
#pragma unroll
            for (int j = 0; j < 8; ++j) acc[i][j] = (f32x4){0.f, 0.f, 0.f, 0.f};
#pragma unroll
        for (int kk = 0; kk < 64; kk += 32) {
            short8 a0 = *(const short8*)&Hs[(w * 32 + r16) * AP + kk + q * 8];
            short8 a1 = *(const short8*)&Hs[(w * 32 + 16 + r16) * AP + kk + q * 8];
#pragma unroll
            for (int j = 0; j < 8; ++j) {
                short8 bf = *(const short8*)&Bs[(j * 16 + r16) * AP + kk + q * 8];
                acc[0][j] = __builtin_amdgcn_mfma_f32_16x16x32_bf16(a0, bf, acc[0][j], 0, 0, 0);
                acc[1][j] = __builtin_amdgcn_mfma_f32_16x16x32_bf16(a1, bf, acc[1][j], 0, 0, 0);
            }
        }
#pragma unroll
        for (int j = 0; j < 8; ++j) {
            int col = j * 16 + r16;
            float bv = b12[col];
            float mv = 0.f;
#pragma unroll
            for (int i = 0; i < 2; ++i)
#pragma unroll
                for (int r = 0; r < 4; ++r)
                    mv = fmaxf(mv, acc[i][j][r] + bv);
            mv = fmaxf(mv, __shfl_xor(mv, 16));
            mv = fmaxf(mv, __shfl_xor(mv, 32));
            if (q == 0)
                f1[(size_t)((m0 >> 5) + w) * 128 + col] = f2bf(mv);
        }
    }
}

// ---------------- Module 2 layer 0 with fused gather (K=192 feat-first) ---------------
// A row r: cols[0..127] = f1[b*256+g2[r]][:], cols[128..130] = xyz1[g2]-ctr, rest 0.
__global__ __launch_bounds__(256) void m2l0_kernel(
    const float* __restrict__ xyz1, const float* __restrict__ nxz2,
    const int* __restrict__ g2, const unsigned short* __restrict__ f1,
    const unsigned short* __restrict__ w20p, const float* __restrict__ bias,
    unsigned short* __restrict__ C) {
    constexpr int AP = 72;
    __shared__ __align__(16) unsigned short As[128 * AP];
    __shared__ __align__(16) unsigned short Bs[128 * AP];
    __shared__ int ribase[128];
    __shared__ unsigned short sxb[128 * 3];
    const int t = threadIdx.x;
    const int lane = t & 63, w = t >> 6;
    const int r16 = lane & 15, q = lane >> 4;
    const int m0 = blockIdx.x * 128;

    if (t < 128) {
        int row = m0 + t, bs = row >> 5, b = bs >> 7, j = g2[row];
        ribase[t] = (b * 256 + j) * 128;
        const float* P = xyz1 + ((size_t)b * S1 + j) * 3;
        const float* Cc = nxz2 + (size_t)bs * 3;
        sxb[t * 3 + 0] = f2bf(P[0] - Cc[0]);
        sxb[t * 3 + 1] = f2bf(P[1] - Cc[1]);
        sxb[t * 3 + 2] = f2bf(P[2] - Cc[2]);
    }
    __syncthreads();

    f32x4 acc[2][8];
#pragma unroll
    for (int i = 0; i < 2; ++i)
#pragma unroll
        for (int j = 0; j < 8; ++j) acc[i][j] = (f32x4){0.f, 0.f, 0.f, 0.f};

    for (int kt = 0; kt < 3; ++kt) {
        const int k0 = kt * 64;
        if (kt < 2) {
            for (int c = t; c < 128 * 8; c += 256) {
                int row = c >> 3, ch = c & 7;
                *(short8*)&As[row * AP + ch * 8] =
                    *(const short8*)&f1[(size_t)ribase[row] + k0 + ch * 8];
            }
        } else {
            for (int c = t; c < 128 * 8; c += 256) {
                int row = c >> 3, ch = c & 7;
                short8 v = (short8){0, 0, 0, 0, 0, 0, 0, 0};
                if (ch == 0) {
                    v[0] = (short)sxb[row * 3 + 0];
                    v[1] = (short)sxb[row * 3 + 1];
                    v[2] = (short)sxb[row * 3 + 2];
                }
                *(short8*)&As[row * AP + ch * 8] = v;
            }
        }
        for (int c = t; c < 128 * 8; c += 256) {
            int row = c >> 3, ch = c & 7;
            *(short8*)&Bs[row * AP + ch * 8] =
                *(const short8*)&w20p[(size_t)row * 192 + k0 + ch * 8];
        }
        __syncthreads();
#pragma unroll
        for (int kk = 0; kk < 64; kk += 32) {
            short8 a0 = *(const short8*)&As[(w * 32 + r16) * AP + kk + q * 8];
            short8 a1 = *(const short8*)&As[(w * 32 + 16 + r16) * AP + kk + q * 8];
#pragma unroll
            for (int j = 0; j < 8; ++j) {
                short8 bf = *(const short8*)&Bs[(j * 16 + r16) * AP + kk + q * 8];
                acc[0][j] = __builtin_amdgcn_mfma_f32_16x16x32_bf16(a0, bf, acc[0][j], 0, 0, 0);
                acc[1][j] = __builtin_amdgcn_mfma_f32_16x16x32_bf16(a1, bf, acc[1][j], 0, 0, 0);
            }
        }
        __syncthreads();
    }
#pragma unroll
    for (int i = 0; i < 2; ++i)
#pragma unroll
        for (int j = 0; j < 8; ++j) {
            int col = j * 16 + r16;
            float bv = bias[col];
#pragma unroll
            for (int r = 0; r < 4; ++r) {
                int row = m0 + w * 32 + i * 16 + q * 4 + r;
                C[(size_t)row * 128 + col] = f2bf(fmaxf(acc[i][j][r] + bv, 0.f));
            }
        }
}

// ---------------- Gather 3: bf16, K padded 259->320 ----------------
__global__ __launch_bounds__(256) void gather3_kernel(const float* __restrict__ nxz2,
                                                      const unsigned short* __restrict__ f2,
                                                      unsigned short* __restrict__ Xg) {
    int u = blockIdx.x * 256 + threadIdx.x;          // < 4096*320
    int r = u / 320, c = u - r * 320;
    unsigned short v;
    if (c < 3)        v = f2bf(nxz2[(size_t)r * 3 + c]);
    else if (c < 259) v = f2[(size_t)r * 256 + (c - 3)];
    else              v = 0;
    Xg[u] = v;
}

// ---------------- bf16 MFMA GEMM: C = relu(X[MxK] * W[NxK]^T + bias) -------------------
template <int BN, bool POOL>
__global__ __launch_bounds__(256) void mfma_gemm(const unsigned short* __restrict__ X,
                                                 const unsigned short* __restrict__ W,
                                                 const float* __restrict__ bias,
                                                 unsigned short* __restrict__ C,
                                                 int M, int N, int K) {
    constexpr int BM = 128, BK = 64;
    constexpr int AP = BK + 8;
    constexpr int NT = BN / 16;
    __shared__ __align__(16) unsigned short As[BM * AP];
    __shared__ __align__(16) unsigned short Bs[BN * AP];
    const int t = threadIdx.x;
    const int lane = t & 63, w = t >> 6;
    const int m0 = blockIdx.x * BM;
    const int n0 = blockIdx.y * BN;
    const int r16 = lane & 15, q = lane >> 4;

    f32x4 acc[2][NT];
#pragma unroll
    for (int i = 0; i < 2; ++i)
#pragma unroll
        for (int j = 0; j < NT; ++j) acc[i][j] = (f32x4){0.f, 0.f, 0.f, 0.f};

    for (int k0 = 0; k0 < K; k0 += BK) {
        for (int c = t; c < BM * (BK / 8); c += 256) {
            int row = c >> 3, ch = c & 7;
            *(short8*)&As[row * AP + ch * 8] =
                *(const short8*)&X[(size_t)(m0 + row) * K + k0 + ch * 8];
        }
        for (int c = t; c < BN * (BK / 8); c += 256) {
            int row = c >> 3, ch = c & 7;
            *(short8*)&Bs[row * AP + ch * 8] =
                *(const short8*)&W[(size_t)(n0 + row) * K + k0 + ch * 8];
        }
        __syncthreads();
#pragma unroll
        for (int kk = 0; kk < BK; kk += 32) {
            short8 a0 = *(const short8*)&As[(w * 32 + r16) * AP + kk + q * 8];
            short8 a1 = *(const short8*)&As[(w * 32 + 16 + r16) * AP + kk + q * 8];
#pragma unroll
            for (int j = 0; j < NT; ++j) {
                short8 bf = *(const short8*)&Bs[(j * 16 + r16) * AP + kk + q * 8];
                acc[0][j] = __builtin_amdgcn_mfma_f32_16x16x32_bf16(a0, bf, acc[0][j], 0, 0, 0);
                acc[1][j] = __builtin_amdgcn_mfma_f32_16x16x32_bf16(a1, bf, acc[1][j], 0, 0, 0);
            }
        }
        __syncthreads();
    }

    if (!POOL) {
#pragma unroll
        for (int i = 0; i < 2; ++i)
#pragma unroll
            for (int j = 0; j < NT; ++j) {
                int col = n0 + j * 16 + r16;
                float bv = bias[col];
#pragma unroll
                for (int r = 0; r < 4; ++r) {
                    int row = m0 + w * 32 + i * 16 + q * 4 + r;
                    C[(size_t)row * N + col] = f2bf(fmaxf(acc[i][j][r] + bv, 0.f));
                }
            }
    } else {
#pragma unroll
        for (int j = 0; j < NT; ++j) {
            int col = n0 + j * 16 + r16;
            float bv = bias[col];
            float mv = 0.f;
#pragma unroll
            for (int i = 0; i < 2; ++i)
#pragma unroll
                for (int r = 0; r < 4; ++r)
                    mv = fmaxf(mv, acc[i][j][r] + bv);
            mv = fmaxf(mv, __shfl_xor(mv, 16));
            mv = fmaxf(mv, __shfl_xor(mv, 32));
            if (q == 0)
                C[(size_t)((m0 >> 5) + w) * N + col] = f2bf(mv);
        }
    }
}

// ---------------- Final max over the 128 points (bf16 in, fp32 out) ----------------
__global__ __launch_bounds__(256) void maxn_kernel(const unsigned short* __restrict__ h,
                                                   float* __restrict__ out) {
    int id = blockIdx.x * 256 + threadIdx.x;  // 32*1024
    int o = id & 1023, b = id >> 10;
    const unsigned short* p = h + (size_t)b * 128 * 1024 + o;
    float m = 0.f;
    for (int n = 0; n < 128; ++n) m = fmaxf(m, bf2f(p[(size_t)n * 1024]));
    out[id] = m;
}

extern "C" void kernel_launch(void* const* d_in, const int* in_sizes, int n_in,
                              void* d_out, int out_size, void* d_ws, size_t ws_size,
                              hipStream_t stream) {
    const float* data = (const float*)d_in[0];
    const float* w10 = (const float*)d_in[1];  const float* b10 = (const float*)d_in[2];
    const float* w11 = (const float*)d_in[3];  const float* b11 = (const float*)d_in[4];
    const float* w12 = (const float*)d_in[5];  const float* b12 = (const float*)d_in[6];
    const float* w20 = (const float*)d_in[7];  const float* b20 = (const float*)d_in[8];
    const float* w21 = (const float*)d_in[9];  const float* b21 = (const float*)d_in[10];
    const float* w22 = (const float*)d_in[11]; const float* b22 = (const float*)d_in[12];
    const float* w30 = (const float*)d_in[13]; const float* b30 = (const float*)d_in[14];
    const float* w31 = (const float*)d_in[15]; const float* b31 = (const float*)d_in[16];
    const float* w32 = (const float*)d_in[17]; const float* b32 = (const float*)d_in[18];
    float* out = (float*)d_out;

    char* ws = (char*)d_ws;
    size_t off = 0;
    auto alloc = [&](size_t bytes) -> void* {
        void* p = ws + off;
        off += (bytes + 255) & ~(size_t)255;
        return p;
    };
    float* nxz1 = (float*)alloc((size_t)BT * S1 * 3 * 4);
    int*   g1   = (int*)  alloc((size_t)BT * S1 * KNB * 4);
    float* nxz2 = (float*)alloc((size_t)BT * S2 * 3 * 4);
    int*   g2   = (int*)  alloc((size_t)BT * S2 * KNB * 4);
    unsigned short* wb  = (unsigned short*)alloc((size_t)823296 * 2);
    unsigned short* f1  = (unsigned short*)alloc((size_t)8192 * 128 * 2);
    unsigned short* f2  = (unsigned short*)alloc((size_t)4096 * 256 * 2);
    unsigned short* xg3 = (unsigned short*)alloc((size_t)4096 * 320 * 2);
    unsigned short* B1  = (unsigned short*)alloc((size_t)131072 * 128 * 2);
    unsigned short* B2  = (unsigned short*)alloc((size_t)131072 * 128 * 2);
    unsigned short* C1  = (unsigned short*)alloc((size_t)4096 * 256 * 2);
    unsigned short* C2  = (unsigned short*)alloc((size_t)4096 * 512 * 2);
    unsigned short* C3  = (unsigned short*)alloc((size_t)4096 * 1024 * 2);

    const unsigned short* w11b = wb + 0;
    const unsigned short* w12b = wb + 4096;
    const unsigned short* w20p = wb + 12288;
    const unsigned short* w21b = wb + 36864;
    const unsigned short* w22b = wb + 53248;
    const unsigned short* w30b = wb + 86016;
    const unsigned short* w31b = wb + 167936;
    const unsigned short* w32b = wb + 299008;

    wconv_kernel<<<(823296 + 255) / 256, 256, 0, stream>>>(w11, w12, w20, w21, w22, w30, w31, w32, wb);

    // ---- module 1 ----
    fps1_kernel<<<BT, 256, 0, stream>>>(data, nxz1);
    ballq1_kernel<<<(BT * S1) / 4, 256, 0, stream>>>(data, nxz1, g1);
    m1_kernel<<<262144 / 128, 256, 0, stream>>>(data, nxz1, g1, w10, b10, w11b, b11, w12b, b12, f1);
    // ---- module 2 ----
    fps2_kernel<<<BT, 64, 0, stream>>>(nxz1, nxz2);
    ballq2_kernel<<<(BT * S2) / 4, 256, 0, stream>>>(nxz1, nxz2, g2);
    m2l0_kernel<<<131072 / 128, 256, 0, stream>>>(nxz1, nxz2, g2, f1, w20p, b20, B1);
    mfma_gemm<128, false><<<dim3(131072 / 128, 1), 256, 0, stream>>>(B1, w21b, b21, B2, 131072, 128, 128);
    mfma_gemm<128, true><<<dim3(131072 / 128, 2), 256, 0, stream>>>(B2, w22b, b22, f2, 131072, 256, 128);
    // ---- module 3 ----
    gather3_kernel<<<(4096 * 320) / 256, 256, 0, stream>>>(nxz2, f2, xg3);
    mfma_gemm<128, false><<<dim3(4096 / 128, 2), 256, 0, stream>>>(xg3, w30b, b30, C1, 4096, 256, 320);
    mfma_gemm<128, false><<<dim3(4096 / 128, 4), 256, 0, stream>>>(C1, w31b, b31, C2, 4096, 512, 256);
    mfma_gemm<128, false><<<dim3(4096 / 128, 8), 256, 0, stream>>>(C2, w32b, b32, C3, 4096, 1024, 512);
    maxn_kernel<<<(BT * 1024) / 256, 256, 0, stream>>>(C3, out);
}

// Round 7
// 533.117 us; speedup vs baseline: 6.0168x; 1.0437x over previous
//
#include <hip/hip_runtime.h>
#include <hip/hip_bf16.h>
#include <cstdint>
#include <cstddef>

// Problem constants: data (4,8,4096,3) -> 32 batches x 4096 points
#define BT 32
#define N1 4096
#define S1 256
#define S2 128
#define KNB 32

typedef __attribute__((ext_vector_type(8))) short short8;   // 8 bf16 in 4 VGPRs
typedef __attribute__((ext_vector_type(4))) float f32x4;

__device__ __forceinline__ float sqdist(float ax, float ay, float az,
                                        float bx, float by, float bz) {
    // exact replication of sum((a-b)**2, axis=-1): mul then left-to-right add, NO fma
    float dx = __fsub_rn(ax, bx), dy = __fsub_rn(ay, by), dz = __fsub_rn(az, bz);
    return __fadd_rn(__fadd_rn(__fmul_rn(dx, dx), __fmul_rn(dy, dy)), __fmul_rn(dz, dz));
}

// bf16 round-to-nearest-even (values here are finite)
__device__ __forceinline__ unsigned short f2bf(float f) {
    unsigned u = __float_as_uint(f);
    return (unsigned short)((u + 0x7FFFu + ((u >> 16) & 1u)) >> 16);
}
__device__ __forceinline__ float bf2f(unsigned short h) {
    return __uint_as_float(((unsigned)h) << 16);
}

// pack (value, index) for argmax-with-first-index-tie-break: distances >= 0 so float
// bits are monotonic as uint; on equal value, larger ~idx == smaller idx wins.
__device__ __forceinline__ unsigned long long packvi(float v, int idx) {
    return ((unsigned long long)__float_as_uint(v) << 32) | (unsigned)(~idx);
}

// DPP row-rotate max for u64: rotations by 1/2/4/8 within 16-lane rows reduce
// commutatively; ~4 cyc per step vs ~40 for ds_swizzle-based __shfl_xor.
template <int CTRL>
__device__ __forceinline__ unsigned long long dppmax(unsigned long long v) {
    int lo = (int)(unsigned)(v & 0xFFFFFFFFull);
    int hi = (int)(unsigned)(v >> 32);
    int lo2 = __builtin_amdgcn_update_dpp(0, lo, CTRL, 0xF, 0xF, false);
    int hi2 = __builtin_amdgcn_update_dpp(0, hi, CTRL, 0xF, 0xF, false);
    unsigned long long o = ((unsigned long long)(unsigned)hi2 << 32) | (unsigned)lo2;
    return o > v ? o : v;
}
#define ROR1 0x121
#define ROR2 0x122
#define ROR4 0x124
#define ROR8 0x128

// ---------------- FPS module 1: N=4096 -> 256, one block/batch, 512 threads ----------
__global__ __launch_bounds__(512) void fps1_kernel(const float* __restrict__ xyz,
                                                   float* __restrict__ nxz) {
    const int b = blockIdx.x, tid = threadIdx.x;
    const int lane = tid & 63, wv = tid >> 6;      // 8 waves
    const float* X = xyz + (size_t)b * (N1 * 3);
    __shared__ float4 s4[N1];                      // 64 KB interleaved coords
    __shared__ unsigned long long slots[2][8];
    __shared__ float hist[S1 * 3];
    float px[8], py[8], pz[8], md[8];
#pragma unroll
    for (int j = 0; j < 8; ++j) {
        int i = tid + 512 * j;
        float x = X[i * 3 + 0], y = X[i * 3 + 1], z = X[i * 3 + 2];
        s4[i] = make_float4(x, y, z, 0.f);
        px[j] = x; py[j] = y; pz[j] = z;
        md[j] = 1e10f;
    }
    if (tid == 0) { hist[0] = X[0]; hist[1] = X[1]; hist[2] = X[2]; }
    __syncthreads();
    float4 c0 = s4[0];
    float lx = c0.x, ly = c0.y, lz = c0.z;
    for (int t = 1; t < S1; ++t) {
        float bv = -1.0f; int bi = 0;
#pragma unroll
        for (int j = 0; j < 8; ++j) {
            float d = sqdist(px[j], py[j], pz[j], lx, ly, lz);
            float m = fminf(md[j], d);
            md[j] = m;
            if (m > bv) { bv = m; bi = tid + 512 * j; }   // ascending flat idx: first max kept
        }
        unsigned long long best = packvi(bv, bi);
        best = dppmax<ROR1>(best);
        best = dppmax<ROR2>(best);
        best = dppmax<ROR4>(best);
        best = dppmax<ROR8>(best);
        { unsigned long long o = __shfl_xor(best, 16); best = o > best ? o : best; }
        { unsigned long long o = __shfl_xor(best, 32); best = o > best ? o : best; }
        if (lane == 0) slots[t & 1][wv] = best;
        __syncthreads();
        unsigned long long w = slots[t & 1][lane & 7];   // rows hold slots 0..7 twice
        w = dppmax<ROR1>(w);
        w = dppmax<ROR2>(w);
        w = dppmax<ROR4>(w);
        int vi = (int)(~(unsigned)w);
        float4 c = s4[vi];
        lx = c.x; ly = c.y; lz = c.z;
        if (tid == 0) { hist[t * 3 + 0] = lx; hist[t * 3 + 1] = ly; hist[t * 3 + 2] = lz; }
    }
    __syncthreads();
    for (int u = tid; u < S1 * 3; u += 512) nxz[(size_t)b * S1 * 3 + u] = hist[u];
}

// ---------------- FPS module 2: N=256 -> 128, ONE WAVE per batch ----------
__global__ __launch_bounds__(64) void fps2_kernel(const float* __restrict__ xyz1,
                                                  float* __restrict__ nxz2) {
    const int b = blockIdx.x, lane = threadIdx.x;
    const float* X = xyz1 + (size_t)b * (S1 * 3);
    __shared__ float4 s4[S1];
    float px[4], py[4], pz[4], md[4];
#pragma unroll
    for (int j = 0; j < 4; ++j) {
        int i = lane + 64 * j;
        float x = X[i * 3 + 0], y = X[i * 3 + 1], z = X[i * 3 + 2];
        s4[i] = make_float4(x, y, z, 0.f);
        px[j] = x; py[j] = y; pz[j] = z;
        md[j] = 1e10f;
    }
    if (lane == 0) {
        nxz2[(size_t)b * S2 * 3 + 0] = X[0];
        nxz2[(size_t)b * S2 * 3 + 1] = X[1];
        nxz2[(size_t)b * S2 * 3 + 2] = X[2];
    }
    // single wave: LDS writes above are wave-synchronous
    float4 cc = s4[0];
    float lx = cc.x, ly = cc.y, lz = cc.z;
    for (int t = 1; t < S2; ++t) {
        float bv = -1.0f; int bi = 0;
#pragma unroll
        for (int j = 0; j < 4; ++j) {
            float d = sqdist(px[j], py[j], pz[j], lx, ly, lz);
            float m = fminf(md[j], d);
            md[j] = m;
            if (m > bv) { bv = m; bi = lane + 64 * j; }
        }
        unsigned long long best = packvi(bv, bi);
        best = dppmax<ROR1>(best);
        best = dppmax<ROR2>(best);
        best = dppmax<ROR4>(best);
        best = dppmax<ROR8>(best);
        { unsigned long long o = __shfl_xor(best, 16); best = o > best ? o : best; }
        { unsigned long long o = __shfl_xor(best, 32); best = o > best ? o : best; }
        int vi = (int)(~(unsigned)best);
        float4 c = s4[vi];
        lx = c.x; ly = c.y; lz = c.z;
        if (lane == 0) {
            float* dst = nxz2 + ((size_t)b * S2 + t) * 3;
            dst[0] = lx; dst[1] = ly; dst[2] = lz;
        }
    }
}

// ---------------- Ball query 1 (wave-per-center): 4096 pts, r=0.2 ----------
__global__ __launch_bounds__(256) void ballq1_kernel(const float* __restrict__ xyz,
                                                     const float* __restrict__ nxz,
                                                     int* __restrict__ gidx) {
    const int wid = (blockIdx.x * 256 + threadIdx.x) >> 6;
    const int lane = threadIdx.x & 63;
    const int b = wid >> 8;
    const float* X = xyz + (size_t)b * (N1 * 3);
    const float* C = nxz + (size_t)wid * 3;
    const float cx = C[0], cy = C[1], cz = C[2];
    const float r2 = (float)(0.2 * 0.2);
    int* G = gidx + (size_t)wid * KNB;
    int cnt = 0, first = 0;
    bool found = false;
    for (int j0 = 0; j0 < N1 && cnt < KNB; j0 += 64) {
        int j = j0 + lane;
        float d2 = sqdist(cx, cy, cz, X[j * 3 + 0], X[j * 3 + 1], X[j * 3 + 2]);
        bool hit = d2 < r2;
        unsigned long long mask = __ballot(hit);
        if (!found && mask) { first = j0 + __builtin_ctzll(mask); found = true; }
        if (hit) {
            int pos = cnt + __popcll(mask & ((1ull << lane) - 1ull));
            if (pos < KNB) G[pos] = j;
        }
        cnt += __popcll(mask);
    }
    if (cnt < KNB) {
        int pad = found ? first : 0;
        if (lane >= cnt && lane < KNB) G[lane] = pad;
    }
}

// ---------------- Ball query 2 (wave-per-center): 256 pts, r=0.4 ----------
__global__ __launch_bounds__(256) void ballq2_kernel(const float* __restrict__ xyz1,
                                                     const float* __restrict__ nxz2,
                                                     int* __restrict__ gidx) {
    const int wid = (blockIdx.x * 256 + threadIdx.x) >> 6;
    const int lane = threadIdx.x & 63;
    const int b = wid >> 7;
    const float* X = xyz1 + (size_t)b * (S1 * 3);
    const float* C = nxz2 + (size_t)wid * 3;
    const float cx = C[0], cy = C[1], cz = C[2];
    const float r2 = (float)(0.4 * 0.4);
    int* G = gidx + (size_t)wid * KNB;
    int cnt = 0, first = 0;
    bool found = false;
    for (int j0 = 0; j0 < S1 && cnt < KNB; j0 += 64) {
        int j = j0 + lane;
        float d2 = sqdist(cx, cy, cz, X[j * 3 + 0], X[j * 3 + 1], X[j * 3 + 2]);
        bool hit = d2 < r2;
        unsigned long long mask = __ballot(hit);
        if (!found && mask) { first = j0 + __builtin_ctzll(mask); found = true; }
        if (hit) {
            int pos = cnt + __popcll(mask & ((1ull << lane) - 1ull));
            if (pos < KNB) G[pos] = j;
        }
        cnt += __popcll(mask);
    }
    if (cnt < KNB) {
        int pad = found ? first : 0;
        if (lane >= cnt && lane < KNB) G[lane] = pad;
    }
}

// ---------------- Weight conversion: fp32 -> bf16 arena, K padded to x64 ----------------
//  w11b@0      64x64   | w12b@4096  128x64 | w20p@12288 128x192 (PERMUTED: feat-first)
//  w21b@36864  128x128 | w22b@53248 256x128| w30b@86016 256x320 (259->320)
//  w31b@167936 512x256 | w32b@299008 1024x512  total 823296
__global__ __launch_bounds__(256) void wconv_kernel(
    const float* __restrict__ w11, const float* __restrict__ w12,
    const float* __restrict__ w20, const float* __restrict__ w21,
    const float* __restrict__ w22, const float* __restrict__ w30,
    const float* __restrict__ w31, const float* __restrict__ w32,
    unsigned short* __restrict__ wb) {
    int u = blockIdx.x * 256 + threadIdx.x;
    if (u >= 823296) return;
    const float* src; int base, Kp, Ko; bool perm20 = false;
    if      (u < 4096)   { src = w11; base = 0;      Kp = 64;  Ko = 64;  }
    else if (u < 12288)  { src = w12; base = 4096;   Kp = 64;  Ko = 64;  }
    else if (u < 36864)  { src = w20; base = 12288;  Kp = 192; Ko = 131; perm20 = true; }
    else if (u < 53248)  { src = w21; base = 36864;  Kp = 128; Ko = 128; }
    else if (u < 86016)  { src = w22; base = 53248;  Kp = 128; Ko = 128; }
    else if (u < 167936) { src = w30; base = 86016;  Kp = 320; Ko = 259; }
    else if (u < 299008) { src = w31; base = 167936; Kp = 256; Ko = 256; }
    else                 { src = w32; base = 299008; Kp = 512; Ko = 512; }
    int local = u - base;
    int n = local / Kp, k = local - n * Kp;
    float v;
    if (perm20) {
        int ksrc = (k < 128) ? (k + 3) : ((k < 131) ? (k - 128) : -1);
        v = (ksrc >= 0) ? src[(size_t)n * 131 + ksrc] : 0.f;
    } else {
        v = (k < Ko) ? src[(size_t)n * Ko + k] : 0.f;
    }
    wb[u] = f2bf(v);
}

// ---------------- Module 1 fused: gather + L0(K=3, VALU) + L1 + L2 MFMA + pool ---------
__global__ __launch_bounds__(256) void m1_kernel(
    const float* __restrict__ xyz, const float* __restrict__ nxz,
    const int* __restrict__ g1,
    const float* __restrict__ w10, const float* __restrict__ b10,
    const unsigned short* __restrict__ w11b, const float* __restrict__ b11,
    const unsigned short* __restrict__ w12b, const float* __restrict__ b12,
    unsigned short* __restrict__ f1) {
    constexpr int AP = 72;
    __shared__ __align__(16) unsigned short As[128 * AP];
    __shared__ __align__(16) unsigned short Hs[128 * AP];
    __shared__ __align__(16) unsigned short Bs[128 * AP];
    __shared__ float sxyz[128 * 3];
    const int t = threadIdx.x;
    const int lane = t & 63, w = t >> 6;
    const int r16 = lane & 15, q = lane >> 4;
    const int m0 = blockIdx.x * 128;

    if (t < 128) {
        int row = m0 + t, bs = row >> 5, b = bs >> 8, j = g1[row];
        const float* P = xyz + ((size_t)b * N1 + j) * 3;
        const float* Cc = nxz + (size_t)bs * 3;
        sxyz[t * 3 + 0] = P[0] - Cc[0];
        sxyz[t * 3 + 1] = P[1] - Cc[1];
        sxyz[t * 3 + 2] = P[2] - Cc[2];
    }
    for (int c = t; c < 64 * 8; c += 256) {
        int row = c >> 3, ch = c & 7;
        *(short8*)&Bs[row * AP + ch * 8] = *(const short8*)&w11b[row * 64 + ch * 8];
    }
    __syncthreads();
    {
        const int r = t >> 1, half = (t & 1) * 32;
        const float x = sxyz[r * 3 + 0], y = sxyz[r * 3 + 1], z = sxyz[r * 3 + 2];
        unsigned short tmp[32];
#pragma unroll
        for (int o = 0; o < 32; ++o) {
            int oo = half + o;
            float acc = b10[oo];
            acc = fmaf(x, w10[oo * 3 + 0], acc);
            acc = fmaf(y, w10[oo * 3 + 1], acc);
            acc = fmaf(z, w10[oo * 3 + 2], acc);
            tmp[o] = f2bf(fmaxf(acc, 0.f));
        }
#pragma unroll
        for (int c2 = 0; c2 < 4; ++c2)
            *(short8*)&As[r * AP + half + c2 * 8] = *(short8*)&tmp[c2 * 8];
    }
    __syncthreads();
    {
        f32x4 acc[2][4];
#pragma unroll
        for (int i = 0; i < 2; ++i)
#pragma unroll
            for (int j = 0; j < 4; ++j) acc[i][j] = (f32x4){0.f, 0.f, 0.f, 0.f};
#pragma unroll
        for (int kk = 0; kk < 64; kk += 32) {
            short8 a0 = *(const short8*)&As[(w * 32 + r16) * AP + kk + q * 8];
            short8 a1 = *(const short8*)&As[(w * 32 + 16 + r16) * AP + kk + q * 8];
#pragma unroll
            for (int j = 0; j < 4; ++j) {
                short8 bf = *(const short8*)&Bs[(j * 16 + r16) * AP + kk + q * 8];
                acc[0][j] = __builtin_amdgcn_mfma_f32_16x16x32_bf16(a0, bf, acc[0][j], 0, 0, 0);
                acc[1][j] = __builtin_amdgcn_mfma_f32_16x16x32_bf16(a1, bf, acc[1][j], 0, 0, 0);
            }
        }
#pragma unroll
        for (int i = 0; i < 2; ++i)
#pragma unroll
            for (int j = 0; j < 4; ++j) {
                int col = j * 16 + r16;
                float bv = b11[col];
#pragma unroll
                for (int r = 0; r < 4; ++r) {
                    int row = w * 32 + i * 16 + q * 4 + r;
                    Hs[row * AP + col] = f2bf(fmaxf(acc[i][j][r] + bv, 0.f));
                }
            }
    }
    __syncthreads();
    for (int c = t; c < 128 * 8; c += 256) {
        int row = c >> 3, ch = c & 7;
        *(short8*)&Bs[row * AP + ch * 8] = *(const short8*)&w12b[row * 64 + ch * 8];
    }
    __syncthreads();
    {
        f32x4 acc[2][8];
#pragma unroll
        for (int i = 0; i < 2; ++i)
#pragma unroll
            for (int j = 0; j < 8; ++j) acc[i][j] = (f32x4){0.f, 0.f, 0.f, 0.f};
#pragma unroll
        for (int kk = 0; kk < 64; kk += 32) {
            short8 a0 = *(const short8*)&Hs[(w * 32 + r16) * AP + kk + q * 8];
            short8 a1 = *(const short8*)&Hs[(w * 32 + 16 + r16) * AP + kk + q * 8];
#pragma unroll
            for (int j = 0; j < 8; ++j) {
                short8 bf = *(const short8*)&Bs[(j * 16 + r16) * AP + kk + q * 8];
                acc[0][j] = __builtin_amdgcn_mfma_f32_16x16x32_bf16(a0, bf, acc[0][j], 0, 0, 0);
                acc[1][j] = __builtin_amdgcn_mfma_f32_16x16x32_bf16(a1, bf, acc[1][j], 0, 0, 0);
            }
        }
#pragma unroll
        for (int j = 0; j < 8; ++j) {
            int col = j * 16 + r16;
            float bv = b12[col];
            float mv = 0.f;
#pragma unroll
            for (int i = 0; i < 2; ++i)
#pragma unroll
                for (int r = 0; r < 4; ++r)
                    mv = fmaxf(mv, acc[i][j][r] + bv);
            mv = fmaxf(mv, __shfl_xor(mv, 16));
            mv = fmaxf(mv, __shfl_xor(mv, 32));
            if (q == 0)
                f1[(size_t)((m0 >> 5) + w) * 128 + col] = f2bf(mv);
        }
    }
}

// ---------------- Module 2 FULLY fused: gather + L0(K=192) + L1(128) + L2(256)+pool ----
// 1024 blocks x 256 thr; block = 128 rows. LDS regions (shorts):
//  R1[18432]: L0 As(0..9216)+Bs(9216..); later H2 (stride 136, 17408)
//  R2[18432]: H1 (stride 136, 17408); later Bs2 (256x72)
__global__ __launch_bounds__(256) void m2_kernel(
    const float* __restrict__ xyz1, const float* __restrict__ nxz2,
    const int* __restrict__ g2, const unsigned short* __restrict__ f1,
    const unsigned short* __restrict__ w20p, const float* __restrict__ b20,
    const unsigned short* __restrict__ w21b, const float* __restrict__ b21,
    const unsigned short* __restrict__ w22b, const float* __restrict__ b22,
    unsigned short* __restrict__ f2) {
    constexpr int AP = 72, HP = 136;
    __shared__ __align__(16) unsigned short smem[36864];   // 72 KB
    unsigned short* R1 = smem;
    unsigned short* R2 = smem + 18432;
    unsigned short* As = R1;
    unsigned short* Bs = R1 + 9216;
    unsigned short* H1 = R2;
    unsigned short* H2 = R1;
    unsigned short* Bs2 = R2;
    __shared__ int ribase[128];
    __shared__ unsigned short sxb[128 * 3];
    const int t = threadIdx.x;
    const int lane = t & 63, w = t >> 6;
    const int r16 = lane & 15, q = lane >> 4;
    const int m0 = blockIdx.x * 128;

    if (t < 128) {
        int row = m0 + t, bs = row >> 5, b = bs >> 7, j = g2[row];
        ribase[t] = (b * 256 + j) * 128;
        const float* P = xyz1 + ((size_t)b * S1 + j) * 3;
        const float* Cc = nxz2 + (size_t)bs * 3;
        sxb[t * 3 + 0] = f2bf(P[0] - Cc[0]);
        sxb[t * 3 + 1] = f2bf(P[1] - Cc[1]);
        sxb[t * 3 + 2] = f2bf(P[2] - Cc[2]);
    }
    __syncthreads();

    // ---- L0: K=192 (3 tiles), N=128 ----
    f32x4 acc[2][8];
#pragma unroll
    for (int i = 0; i < 2; ++i)
#pragma unroll
        for (int j = 0; j < 8; ++j) acc[i][j] = (f32x4){0.f, 0.f, 0.f, 0.f};
    for (int kt = 0; kt < 3; ++kt) {
        const int k0 = kt * 64;
        if (kt < 2) {
            for (int c = t; c < 128 * 8; c += 256) {
                int row = c >> 3, ch = c & 7;
                *(short8*)&As[row * AP + ch * 8] =
                    *(const short8*)&f1[(size_t)ribase[row] + k0 + ch * 8];
            }
        } else {
            for (int c = t; c < 128 * 8; c += 256) {
                int row = c >> 3, ch = c & 7;
                short8 v = (short8){0, 0, 0, 0, 0, 0, 0, 0};
                if (ch == 0) {
                    v[0] = (short)sxb[row * 3 + 0];
                    v[1] = (short)sxb[row * 3 + 1];
                    v[2] = (short)sxb[row * 3 + 2];
                }
                *(short8*)&As[row * AP + ch * 8] = v;
            }
        }
        for (int c = t; c < 128 * 8; c += 256) {
            int row = c >> 3, ch = c & 7;
            *(short8*)&Bs[row * AP + ch * 8] =
                *(const short8*)&w20p[(size_t)row * 192 + k0 + ch * 8];
        }
        __syncthreads();
#pragma unroll
        for (int kk = 0; kk < 64; kk += 32) {
            short8 a0 = *(const short8*)&As[(w * 32 + r16) * AP + kk + q * 8];
            short8 a1 = *(const short8*)&As[(w * 32 + 16 + r16) * AP + kk + q * 8];
#pragma unroll
            for (int j = 0; j < 8; ++j) {
                short8 bf = *(const short8*)&Bs[(j * 16 + r16) * AP + kk + q * 8];
                acc[0][j] = __builtin_amdgcn_mfma_f32_16x16x32_bf16(a0, bf, acc[0][j], 0, 0, 0);
                acc[1][j] = __builtin_amdgcn_mfma_f32_16x16x32_bf16(a1, bf, acc[1][j], 0, 0, 0);
            }
        }
        __syncthreads();
    }
    // write H1 = relu(acc + b20), bf16, stride 136 (R2)
#pragma unroll
    for (int i = 0; i < 2; ++i)
#pragma unroll
        for (int j = 0; j < 8; ++j) {
            int col = j * 16 + r16;
            float bv = b20[col];
#pragma unroll
            for (int r = 0; r < 4; ++r) {
                int row = w * 32 + i * 16 + q * 4 + r;
                H1[row * HP + col] = f2bf(fmaxf(acc[i][j][r] + bv, 0.f));
            }
        }
    __syncthreads();

    // ---- L1: K=128 (2 tiles), N=128; A from H1, Bs staged in R1 head ----
#pragma unroll
    for (int i = 0; i < 2; ++i)
#pragma unroll
        for (int j = 0; j < 8; ++j) acc[i][j] = (f32x4){0.f, 0.f, 0.f, 0.f};
    for (int kt = 0; kt < 2; ++kt) {
        const int k0 = kt * 64;
        for (int c = t; c < 128 * 8; c += 256) {
            int row = c >> 3, ch = c & 7;
            *(short8*)&As[row * AP + ch * 8] =
                *(const short8*)&w21b[(size_t)row * 128 + k0 + ch * 8];
        }
        __syncthreads();
#pragma unroll
        for (int kk = 0; kk < 64; kk += 32) {
            short8 a0 = *(const short8*)&H1[(w * 32 + r16) * HP + k0 + kk + q * 8];
            short8 a1 = *(const short8*)&H1[(w * 32 + 16 + r16) * HP + k0 + kk + q * 8];
#pragma unroll
            for (int j = 0; j < 8; ++j) {
                short8 bf = *(const short8*)&As[(j * 16 + r16) * AP + kk + q * 8];
                acc[0][j] = __builtin_amdgcn_mfma_f32_16x16x32_bf16(a0, bf, acc[0][j], 0, 0, 0);
                acc[1][j] = __builtin_amdgcn_mfma_f32_16x16x32_bf16(a1, bf, acc[1][j], 0, 0, 0);
            }
        }
        __syncthreads();
    }
    // write H2 = relu(acc + b21) into R1 (As/Bs dead)
#pragma unroll
    for (int i = 0; i < 2; ++i)
#pragma unroll
        for (int j = 0; j < 8; ++j) {
            int col = j * 16 + r16;
            float bv = b21[col];
#pragma unroll
            for (int r = 0; r < 4; ++r) {
                int row = w * 32 + i * 16 + q * 4 + r;
                H2[row * HP + col] = f2bf(fmaxf(acc[i][j][r] + bv, 0.f));
            }
        }
    __syncthreads();

    // ---- L2: K=128 (2 tiles), N=256; A from H2 (R1), Bs2 in R2 (H1 dead) + pool ----
    f32x4 acc2[2][16];
#pragma unroll
    for (int i = 0; i < 2; ++i)
#pragma unroll
        for (int j = 0; j < 16; ++j) acc2[i][j] = (f32x4){0.f, 0.f, 0.f, 0.f};
    for (int kt = 0; kt < 2; ++kt) {
        const int k0 = kt * 64;
        for (int c = t; c < 256 * 8; c += 256) {
            int row = c >> 3, ch = c & 7;
            *(short8*)&Bs2[row * AP + ch * 8] =
                *(const short8*)&w22b[(size_t)row * 128 + k0 + ch * 8];
        }
        __syncthreads();
#pragma unroll
        for (int kk = 0; kk < 64; kk += 32) {
            short8 a0 = *(const short8*)&H2[(w * 32 + r16) * HP + k0 + kk + q * 8];
            short8 a1 = *(const short8*)&H2[(w * 32 + 16 + r16) * HP + k0 + kk + q * 8];
#pragma unroll
            for (int j = 0; j < 16; ++j) {
                short8 bf = *(const short8*)&Bs2[(j * 16 + r16) * AP + kk + q * 8];
                acc2[0][j] = __builtin_amdgcn_mfma_f32_16x16x32_bf16(a0, bf, acc2[0][j], 0, 0, 0);
                acc2[1][j] = __builtin_amdgcn_mfma_f32_16x16x32_bf16(a1, bf, acc2[1][j], 0, 0, 0);
            }
        }
        __syncthreads();
    }
    // pool epilogue: wave w = pool group (m0>>5)+w
#pragma unroll
    for (int j = 0; j < 16; ++j) {
        int col = j * 16 + r16;
        float bv = b22[col];
        float mv = 0.f;
#pragma unroll
        for (int i = 0; i < 2; ++i)
#pragma unroll
            for (int r = 0; r < 4; ++r)
                mv = fmaxf(mv, acc2[i][j][r] + bv);
        mv = fmaxf(mv, __shfl_xor(mv, 16));
        mv = fmaxf(mv, __shfl_xor(mv, 32));
        if (q == 0)
            f2[(size_t)((m0 >> 5) + w) * 256 + col] = f2bf(mv);
    }
}

// ---------------- Gather 3: bf16, K padded 259->320 ----------------
__global__ __launch_bounds__(256) void gather3_kernel(const float* __restrict__ nxz2,
                                                      const unsigned short* __restrict__ f2,
                                                      unsigned short* __restrict__ Xg) {
    int u = blockIdx.x * 256 + threadIdx.x;          // < 4096*320
    int r = u / 320, c = u - r * 320;
    unsigned short v;
    if (c < 3)        v = f2bf(nxz2[(size_t)r * 3 + c]);
    else if (c < 259) v = f2[(size_t)r * 256 + (c - 3)];
    else              v = 0;
    Xg[u] = v;
}

// ---------------- bf16 MFMA GEMM: C = relu(X[MxK] * W[NxK]^T + bias) -------------------
template <int BN, bool POOL>
__global__ __launch_bounds__(256) void mfma_gemm(const unsigned short* __restrict__ X,
                                                 const unsigned short* __restrict__ W,
                                                 const float* __restrict__ bias,
                                                 unsigned short* __restrict__ C,
                                                 int M, int N, int K) {
    constexpr int BM = 128, BK = 64;
    constexpr int AP = BK + 8;
    constexpr int NT = BN / 16;
    __shared__ __align__(16) unsigned short As[BM * AP];
    __shared__ __align__(16) unsigned short Bs[BN * AP];
    const int t = threadIdx.x;
    const int lane = t & 63, w = t >> 6;
    const int m0 = blockIdx.x * BM;
    const int n0 = blockIdx.y * BN;
    const int r16 = lane & 15, q = lane >> 4;

    f32x4 acc[2][NT];
#pragma unroll
    for (int i = 0; i < 2; ++i)
#pragma unroll
        for (int j = 0; j < NT; ++j) acc[i][j] = (f32x4){0.f, 0.f, 0.f, 0.f};

    for (int k0 = 0; k0 < K; k0 += BK) {
        for (int c = t; c < BM * (BK / 8); c += 256) {
            int row = c >> 3, ch = c & 7;
            *(short8*)&As[row * AP + ch * 8] =
                *(const short8*)&X[(size_t)(m0 + row) * K + k0 + ch * 8];
        }
        for (int c = t; c < BN * (BK / 8); c += 256) {
            int row = c >> 3, ch = c & 7;
            *(short8*)&Bs[row * AP + ch * 8] =
                *(const short8*)&W[(size_t)(n0 + row) * K + k0 + ch * 8];
        }
        __syncthreads();
#pragma unroll
        for (int kk = 0; kk < BK; kk += 32) {
            short8 a0 = *(const short8*)&As[(w * 32 + r16) * AP + kk + q * 8];
            short8 a1 = *(const short8*)&As[(w * 32 + 16 + r16) * AP + kk + q * 8];
#pragma unroll
            for (int j = 0; j < NT; ++j) {
                short8 bf = *(const short8*)&Bs[(j * 16 + r16) * AP + kk + q * 8];
                acc[0][j] = __builtin_amdgcn_mfma_f32_16x16x32_bf16(a0, bf, acc[0][j], 0, 0, 0);
                acc[1][j] = __builtin_amdgcn_mfma_f32_16x16x32_bf16(a1, bf, acc[1][j], 0, 0, 0);
            }
        }
        __syncthreads();
    }

    if (!POOL) {
#pragma unroll
        for (int i = 0; i < 2; ++i)
#pragma unroll
            for (int j = 0; j < NT; ++j) {
                int col = n0 + j * 16 + r16;
                float bv = bias[col];
#pragma unroll
                for (int r = 0; r < 4; ++r) {
                    int row = m0 + w * 32 + i * 16 + q * 4 + r;
                    C[(size_t)row * N + col] = f2bf(fmaxf(acc[i][j][r] + bv, 0.f));
                }
            }
    } else {
#pragma unroll
        for (int j = 0; j < NT; ++j) {
            int col = n0 + j * 16 + r16;
            float bv = bias[col];
            float mv = 0.f;
#pragma unroll
            for (int i = 0; i < 2; ++i)
#pragma unroll
                for (int r = 0; r < 4; ++r)
                    mv = fmaxf(mv, acc[i][j][r] + bv);
            mv = fmaxf(mv, __shfl_xor(mv, 16));
            mv = fmaxf(mv, __shfl_xor(mv, 32));
            if (q == 0)
                C[(size_t)((m0 >> 5) + w) * N + col] = f2bf(mv);
        }
    }
}

// ---------------- Final max over the 128 points (bf16 in, fp32 out) ----------------
__global__ __launch_bounds__(256) void maxn_kernel(const unsigned short* __restrict__ h,
                                                   float* __restrict__ out) {
    int id = blockIdx.x * 256 + threadIdx.x;  // 32*1024
    int o = id & 1023, b = id >> 10;
    const unsigned short* p = h + (size_t)b * 128 * 1024 + o;
    float m = 0.f;
    for (int n = 0; n < 128; ++n) m = fmaxf(m, bf2f(p[(size_t)n * 1024]));
    out[id] = m;
}

extern "C" void kernel_launch(void* const* d_in, const int* in_sizes, int n_in,
                              void* d_out, int out_size, void* d_ws, size_t ws_size,
                              hipStream_t stream) {
    const float* data = (const float*)d_in[0];
    const float* w10 = (const float*)d_in[1];  const float* b10 = (const float*)d_in[2];
    const float* w11 = (const float*)d_in[3];  const float* b11 = (const float*)d_in[4];
    const float* w12 = (const float*)d_in[5];  const float* b12 = (const float*)d_in[6];
    const float* w20 = (const float*)d_in[7];  const float* b20 = (const float*)d_in[8];
    const float* w21 = (const float*)d_in[9];  const float* b21 = (const float*)d_in[10];
    const float* w22 = (const float*)d_in[11]; const float* b22 = (const float*)d_in[12];
    const float* w30 = (const float*)d_in[13]; const float* b30 = (const float*)d_in[14];
    const float* w31 = (const float*)d_in[15]; const float* b31 = (const float*)d_in[16];
    const float* w32 = (const float*)d_in[17]; const float* b32 = (const float*)d_in[18];
    float* out = (float*)d_out;

    char* ws = (char*)d_ws;
    size_t off = 0;
    auto alloc = [&](size_t bytes) -> void* {
        void* p = ws + off;
        off += (bytes + 255) & ~(size_t)255;
        return p;
    };
    float* nxz1 = (float*)alloc((size_t)BT * S1 * 3 * 4);
    int*   g1   = (int*)  alloc((size_t)BT * S1 * KNB * 4);
    float* nxz2 = (float*)alloc((size_t)BT * S2 * 3 * 4);
    int*   g2   = (int*)  alloc((size_t)BT * S2 * KNB * 4);
    unsigned short* wb  = (unsigned short*)alloc((size_t)823296 * 2);
    unsigned short* f1  = (unsigned short*)alloc((size_t)8192 * 128 * 2);
    unsigned short* f2  = (unsigned short*)alloc((size_t)4096 * 256 * 2);
    unsigned short* xg3 = (unsigned short*)alloc((size_t)4096 * 320 * 2);
    unsigned short* C1  = (unsigned short*)alloc((size_t)4096 * 256 * 2);
    unsigned short* C2  = (unsigned short*)alloc((size_t)4096 * 512 * 2);
    unsigned short* C3  = (unsigned short*)alloc((size_t)4096 * 1024 * 2);

    const unsigned short* w11b = wb + 0;
    const unsigned short* w12b = wb + 4096;
    const unsigned short* w20p = wb + 12288;
    const unsigned short* w21b = wb + 36864;
    const unsigned short* w22b = wb + 53248;
    const unsigned short* w30b = wb + 86016;
    const unsigned short* w31b = wb + 167936;
    const unsigned short* w32b = wb + 299008;

    wconv_kernel<<<(823296 + 255) / 256, 256, 0, stream>>>(w11, w12, w20, w21, w22, w30, w31, w32, wb);

    // ---- module 1 ----
    fps1_kernel<<<BT, 512, 0, stream>>>(data, nxz1);
    ballq1_kernel<<<(BT * S1) / 4, 256, 0, stream>>>(data, nxz1, g1);
    m1_kernel<<<262144 / 128, 256, 0, stream>>>(data, nxz1, g1, w10, b10, w11b, b11, w12b, b12, f1);
    // ---- module 2 ----
    fps2_kernel<<<BT, 64, 0, stream>>>(nxz1, nxz2);
    ballq2_kernel<<<(BT * S2) / 4, 256, 0, stream>>>(nxz1, nxz2, g2);
    m2_kernel<<<131072 / 128, 256, 0, stream>>>(nxz1, nxz2, g2, f1, w20p, b20, w21b, b21, w22b, b22, f2);
    // ---- module 3 ----
    gather3_kernel<<<(4096 * 320) / 256, 256, 0, stream>>>(nxz2, f2, xg3);
    mfma_gemm<128, false><<<dim3(4096 / 128, 2), 256, 0, stream>>>(xg3, w30b, b30, C1, 4096, 256, 320);
    mfma_gemm<128, false><<<dim3(4096 / 128, 4), 256, 0, stream>>>(C1, w31b, b31, C2, 4096, 512, 256);
    mfma_gemm<128, false><<<dim3(4096 / 128, 8), 256, 0, stream>>>(C2, w32b, b32, C3, 4096, 1024, 512);
    maxn_kernel<<<(BT * 1024) / 256, 256, 0, stream>>>(C3, out);
}